// Round 1
// baseline (2251.956 us; speedup 1.0000x reference)
//
#include <hip/hip_runtime.h>
#include <stdint.h>

#define T_SEQ 2048
#define HIDN  4096
#define NH    32
#define NKV   8
#define DH    128
#define INTER 14336
#define QKV_N 6144   /* (32+16)*128 */
#define EPSR  1e-5f
#define SCALE 0.08838834764831845f  /* 1/sqrt(128) */

typedef __bf16 bf16x8 __attribute__((ext_vector_type(8)));
typedef float  f32x4  __attribute__((ext_vector_type(4)));

__device__ __forceinline__ f32x4 mfma16(bf16x8 a, bf16x8 b, f32x4 c) {
  return __builtin_amdgcn_mfma_f32_16x16x32_bf16(a, b, c, 0, 0, 0);
}

__device__ __forceinline__ void glds16(const void* g, void* l) {
  __builtin_amdgcn_global_load_lds(
      (__attribute__((address_space(1))) void*)g,
      (__attribute__((address_space(3))) void*)l,
      16, 0, 0);
}

// ---------------- RMSNorm: fp32 in -> bf16 out ----------------
__global__ __launch_bounds__(256) void rmsnorm_kernel(
    const float* __restrict__ x, const float* __restrict__ w,
    __bf16* __restrict__ y) {
  const int row = blockIdx.x, tid = threadIdx.x;
  const float* xr = x + (size_t)row * HIDN + tid * 16;
  float4 v0 = ((const float4*)xr)[0];
  float4 v1 = ((const float4*)xr)[1];
  float4 v2 = ((const float4*)xr)[2];
  float4 v3 = ((const float4*)xr)[3];
  float ss = v0.x*v0.x + v0.y*v0.y + v0.z*v0.z + v0.w*v0.w
           + v1.x*v1.x + v1.y*v1.y + v1.z*v1.z + v1.w*v1.w
           + v2.x*v2.x + v2.y*v2.y + v2.z*v2.z + v2.w*v2.w
           + v3.x*v3.x + v3.y*v3.y + v3.z*v3.z + v3.w*v3.w;
  #pragma unroll
  for (int off = 32; off >= 1; off >>= 1) ss += __shfl_xor(ss, off, 64);
  __shared__ float red[4];
  if ((tid & 63) == 0) red[tid >> 6] = ss;
  __syncthreads();
  float rn = rsqrtf((red[0] + red[1] + red[2] + red[3]) * (1.0f / HIDN) + EPSR);
  const float* wr = w + tid * 16;
  float4 w0 = ((const float4*)wr)[0];
  float4 w1v = ((const float4*)wr)[1];
  float4 w2v = ((const float4*)wr)[2];
  float4 w3v = ((const float4*)wr)[3];
  bf16x8 o0, o1;
  o0[0]=(__bf16)(v0.x*rn*w0.x);  o0[1]=(__bf16)(v0.y*rn*w0.y);
  o0[2]=(__bf16)(v0.z*rn*w0.z);  o0[3]=(__bf16)(v0.w*rn*w0.w);
  o0[4]=(__bf16)(v1.x*rn*w1v.x); o0[5]=(__bf16)(v1.y*rn*w1v.y);
  o0[6]=(__bf16)(v1.z*rn*w1v.z); o0[7]=(__bf16)(v1.w*rn*w1v.w);
  o1[0]=(__bf16)(v2.x*rn*w2v.x); o1[1]=(__bf16)(v2.y*rn*w2v.y);
  o1[2]=(__bf16)(v2.z*rn*w2v.z); o1[3]=(__bf16)(v2.w*rn*w2v.w);
  o1[4]=(__bf16)(v3.x*rn*w3v.x); o1[5]=(__bf16)(v3.y*rn*w3v.y);
  o1[6]=(__bf16)(v3.z*rn*w3v.z); o1[7]=(__bf16)(v3.w*rn*w3v.w);
  __bf16* yo = y + (size_t)row * HIDN + tid * 16;
  *(bf16x8*)(yo)     = o0;
  *(bf16x8*)(yo + 8) = o1;
}

// ---------------- GEMM: C[M,N] = A[M,K](bf16) * B[N,K](fp32)^T ----------------
// EPI: 0 = write f32, 1 = write bf16, 2 = write f32 + resid
template<int EPI>
__global__ __launch_bounds__(256) void gemm_bt_kernel(
    const __bf16* __restrict__ A, const float* __restrict__ B,
    void* __restrict__ Cout, const float* __restrict__ resid,
    int M, int N, int Kd) {
  __shared__ __align__(16) __bf16 As[128 * 32];
  __shared__ __align__(16) __bf16 Bs[128 * 32];
  const int tid = threadIdx.x;
  const int lane = tid & 63;
  const int wv = tid >> 6;
  const int wm = wv >> 1, wn = wv & 1;

  // remap so 16 consecutively-dispatched blocks share the B panel (bx)
  int lin = blockIdx.y * gridDim.x + blockIdx.x;
  int gy = gridDim.y;
  int by = lin % gy, bx = lin / gy;
  const int m0 = by * 128, n0 = bx * 128;

  f32x4 acc[4][4] = {};

  const int brow = tid >> 1;
  const int bhalf = (tid & 1) * 16;
  const float* bsrc = B + (size_t)(n0 + brow) * Kd + bhalf;
  char* bdst0 = (char*)Bs + brow * 64 + ((bhalf * 2)      ^ ((brow & 3) << 4));
  char* bdst1 = (char*)Bs + brow * 64 + ((bhalf * 2 + 16) ^ ((brow & 3) << 4));

  for (int k0 = 0; k0 < Kd; k0 += 32) {
    __syncthreads();
    // stage A (bf16) via global_load_lds, pre-swizzled source
    #pragma unroll
    for (int i = 0; i < 2; i++) {
      int idx = i * 256 + tid;
      int row = idx >> 2;
      int cb = ((idx & 3) * 16) ^ ((row & 3) << 4);
      glds16((const char*)(A + (size_t)(m0 + row) * Kd + k0) + cb,
             (char*)As + idx * 16);
    }
    // stage B (fp32 -> bf16), swizzled ds_write
    {
      const float* bp = bsrc + k0;
      float4 f0 = ((const float4*)bp)[0];
      float4 f1 = ((const float4*)bp)[1];
      float4 f2 = ((const float4*)bp)[2];
      float4 f3 = ((const float4*)bp)[3];
      bf16x8 p0, p1;
      p0[0]=(__bf16)f0.x; p0[1]=(__bf16)f0.y; p0[2]=(__bf16)f0.z; p0[3]=(__bf16)f0.w;
      p0[4]=(__bf16)f1.x; p0[5]=(__bf16)f1.y; p0[6]=(__bf16)f1.z; p0[7]=(__bf16)f1.w;
      p1[0]=(__bf16)f2.x; p1[1]=(__bf16)f2.y; p1[2]=(__bf16)f2.z; p1[3]=(__bf16)f2.w;
      p1[4]=(__bf16)f3.x; p1[5]=(__bf16)f3.y; p1[6]=(__bf16)f3.z; p1[7]=(__bf16)f3.w;
      *(bf16x8*)bdst0 = p0;
      *(bf16x8*)bdst1 = p1;
    }
    __syncthreads();
    bf16x8 af[4], bfr[4];
    #pragma unroll
    for (int t2 = 0; t2 < 4; t2++) {
      int ar = wm * 64 + t2 * 16 + (lane & 15);
      af[t2] = *(const bf16x8*)((char*)As + ar * 64 + ((((lane >> 4) * 16)) ^ ((ar & 3) << 4)));
      int br = wn * 64 + t2 * 16 + (lane & 15);
      bfr[t2] = *(const bf16x8*)((char*)Bs + br * 64 + ((((lane >> 4) * 16)) ^ ((br & 3) << 4)));
    }
    #pragma unroll
    for (int mt = 0; mt < 4; mt++)
      #pragma unroll
      for (int nt = 0; nt < 4; nt++)
        acc[mt][nt] = mfma16(af[mt], bfr[nt], acc[mt][nt]);
  }

  const int rbase = m0 + wm * 64 + ((lane >> 4) << 2);
  const int cbase = n0 + wn * 64 + (lane & 15);
  #pragma unroll
  for (int mt = 0; mt < 4; mt++) {
    #pragma unroll
    for (int r = 0; r < 4; r++) {
      int rr = rbase + mt * 16 + r;
      #pragma unroll
      for (int nt = 0; nt < 4; nt++) {
        int cc = cbase + nt * 16;
        size_t ix = (size_t)rr * N + cc;
        float val = acc[mt][nt][r];
        if (EPI == 0)      ((float*)Cout)[ix] = val;
        else if (EPI == 1) ((__bf16*)Cout)[ix] = (__bf16)val;
        else               ((float*)Cout)[ix] = val + resid[ix];
      }
    }
  }
}

// ---------------- RoPE: qkv(bf16) -> q_r, k_r (bf16) ----------------
__global__ __launch_bounds__(256) void rope_kernel(
    const __bf16* __restrict__ qkv, __bf16* __restrict__ q_r,
    __bf16* __restrict__ k_r) {
  const int t = blockIdx.x, tid = threadIdx.x;
  __shared__ float cs[64], sn[64];
  if (tid < 64) {
    float inv = exp2f(-(float)tid * (19.931568569324174f / 64.0f)); // theta=1e6
    float f = (float)t * inv;
    cs[tid] = cosf(f);
    sn[tid] = sinf(f);
  }
  __syncthreads();
  const __bf16* row = qkv + (size_t)t * QKV_N;
  for (int it = tid; it < 40 * 64; it += 256) {
    int hh = it >> 6, i = it & 63;
    float x1 = (float)row[hh * 128 + i];
    float x2 = (float)row[hh * 128 + 64 + i];
    float c = cs[i], s = sn[i];
    float o1 = x1 * c - x2 * s;
    float o2 = x2 * c + x1 * s;
    if (hh < NH) {
      __bf16* qo = q_r + (size_t)t * HIDN + hh * 128;
      qo[i] = (__bf16)o1;
      qo[64 + i] = (__bf16)o2;
    } else {
      __bf16* ko = k_r + (size_t)t * (NKV * DH) + (hh - NH) * 128;
      ko[i] = (__bf16)o1;
      ko[64 + i] = (__bf16)o2;
    }
  }
}

// ---------------- Flash attention (causal, GQA) ----------------
__global__ __launch_bounds__(256) void attn_kernel(
    const __bf16* __restrict__ q_r, const __bf16* __restrict__ k_r,
    const __bf16* __restrict__ qkv, __bf16* __restrict__ attn_o) {
  __shared__ __align__(16) __bf16 Ks[32 * 128];
  __shared__ __align__(16) __bf16 Vt[128][40];
  __shared__ __align__(16) __bf16 Pl[4][16][40];

  const int tid = threadIdx.x;
  const int lane = tid & 63, wv = tid >> 6;
  const int qt = blockIdx.x, h = blockIdx.y;
  const int kh = h >> 2;  // G = 4
  const int q0b = qt * 64;
  const int q0w = q0b + wv * 16;

  bf16x8 qf[4];
  {
    const __bf16* qp = q_r + (size_t)(q0w + (lane & 15)) * HIDN + h * DH + ((lane >> 4) << 3);
    #pragma unroll
    for (int kk = 0; kk < 4; kk++) qf[kk] = *(const bf16x8*)(qp + kk * 32);
  }

  f32x4 o[8] = {};
  float mrun[4] = {-1e30f, -1e30f, -1e30f, -1e30f};
  float lrun[4] = {0.f, 0.f, 0.f, 0.f};

  const int kv_end = q0b + 64;
  for (int kv0 = 0; kv0 < kv_end; kv0 += 32) {
    __syncthreads();
    // stage K (32x128) via global_load_lds, xor-swizzled ((row&7)<<4)
    #pragma unroll
    for (int i = 0; i < 2; i++) {
      int idx = i * 256 + tid;
      int row = idx >> 4;
      int cb = ((idx & 15) * 16) ^ ((row & 7) << 4);
      glds16((const char*)(k_r + (size_t)(kv0 + row) * (NKV * DH) + kh * DH) + cb,
             (char*)Ks + idx * 16);
    }
    // stage V transposed into padded Vt[128][40]
    {
      int d = tid & 127;
      int kvh = (tid >> 7) << 4;
      const __bf16* vp = qkv + (size_t)(kv0 + kvh) * QKV_N + (NH + NKV) * DH + kh * DH + d;
      #pragma unroll
      for (int j = 0; j < 16; j++) Vt[d][kvh + j] = vp[(size_t)j * QKV_N];
    }
    __syncthreads();

    if (q0w + 15 >= kv0) {
      f32x4 s[2] = {};
      #pragma unroll
      for (int kk = 0; kk < 4; kk++) {
        #pragma unroll
        for (int jt = 0; jt < 2; jt++) {
          int row = jt * 16 + (lane & 15);
          int cb = (kk * 64 + ((lane >> 4) << 4)) ^ ((row & 7) << 4);
          bf16x8 kf = *(const bf16x8*)((char*)Ks + row * 256 + cb);
          s[jt] = mfma16(qf[kk], kf, s[jt]);
        }
      }
      float p0[4], p1[4], mx[4];
      const bool need_mask = (kv0 + 31) > q0w;
      #pragma unroll
      for (int r = 0; r < 4; r++) {
        float a = s[0][r] * SCALE, b = s[1][r] * SCALE;
        if (need_mask) {
          int qpos = q0w + ((lane >> 4) << 2) + r;
          int kva = kv0 + (lane & 15);
          if (kva > qpos) a = -1e30f;
          if (kva + 16 > qpos) b = -1e30f;
        }
        p0[r] = a; p1[r] = b;
        mx[r] = fmaxf(a, b);
      }
      #pragma unroll
      for (int r = 0; r < 4; r++) {
        #pragma unroll
        for (int off = 1; off < 16; off <<= 1)
          mx[r] = fmaxf(mx[r], __shfl_xor(mx[r], off, 64));
        float mn = fmaxf(mrun[r], mx[r]);
        float corr = __expf(mrun[r] - mn);
        mrun[r] = mn;
        p0[r] = __expf(p0[r] - mn);
        p1[r] = __expf(p1[r] - mn);
        float ps = p0[r] + p1[r];
        #pragma unroll
        for (int off = 1; off < 16; off <<= 1) ps += __shfl_xor(ps, off, 64);
        lrun[r] = lrun[r] * corr + ps;
        #pragma unroll
        for (int nt = 0; nt < 8; nt++) o[nt][r] *= corr;
        int prow = ((lane >> 4) << 2) + r;
        Pl[wv][prow][lane & 15]      = (__bf16)p0[r];
        Pl[wv][prow][16 + (lane & 15)] = (__bf16)p1[r];
      }
      bf16x8 pf = *(const bf16x8*)&Pl[wv][lane & 15][(lane >> 4) << 3];
      #pragma unroll
      for (int nt = 0; nt < 8; nt++) {
        bf16x8 vf = *(const bf16x8*)&Vt[nt * 16 + (lane & 15)][(lane >> 4) << 3];
        o[nt] = mfma16(pf, vf, o[nt]);
      }
    }
  }

  #pragma unroll
  for (int nt = 0; nt < 8; nt++) {
    #pragma unroll
    for (int r = 0; r < 4; r++) {
      int qrow = q0w + ((lane >> 4) << 2) + r;
      int d = nt * 16 + (lane & 15);
      attn_o[(size_t)qrow * HIDN + h * DH + d] = (__bf16)(o[nt][r] / lrun[r]);
    }
  }
}

// ---------------- SwiGLU elementwise: g = silu(u) * v ----------------
__global__ __launch_bounds__(256) void silu_mul_kernel(
    const __bf16* __restrict__ u, const __bf16* __restrict__ v,
    __bf16* __restrict__ g, long n) {
  long stride = (long)gridDim.x * 256 * 8;
  for (long i = ((long)blockIdx.x * 256 + threadIdx.x) * 8; i < n; i += stride) {
    bf16x8 uu = *(const bf16x8*)(u + i);
    bf16x8 vv = *(const bf16x8*)(v + i);
    bf16x8 gg;
    #pragma unroll
    for (int j = 0; j < 8; j++) {
      float x = (float)uu[j];
      float y = (float)vv[j];
      float sl = x / (1.0f + __expf(-x));
      gg[j] = (__bf16)(sl * y);
    }
    *(bf16x8*)(g + i) = gg;
  }
}

extern "C" void kernel_launch(void* const* d_in, const int* in_sizes, int n_in,
                              void* d_out, int out_size, void* d_ws, size_t ws_size,
                              hipStream_t stream) {
  const float* hidden = (const float*)d_in[0];
  // d_in[1] position_ids == arange(T); row index used directly
  const float* wqkv = (const float*)d_in[2];
  const float* wo   = (const float*)d_in[3];
  const float* w1   = (const float*)d_in[4];
  const float* w3   = (const float*)d_in[5];
  const float* w2   = (const float*)d_in[6];
  const float* anw  = (const float*)d_in[7];
  const float* fnw  = (const float*)d_in[8];

  char* ws = (char*)d_ws;
  // overlay layout (bytes):
  //  [0, 58,720,256)  : xn1(16.7M) | qkv(25.2M) | q_r(16.8M)   -- later reused as u/g
  const size_t SZ_XN   = (size_t)T_SEQ * HIDN * 2;      // 16,777,216
  const size_t SZ_QKV  = (size_t)T_SEQ * QKV_N * 2;     // 25,165,824
  const size_t SZ_KR   = (size_t)T_SEQ * NKV * DH * 2;  //  4,194,304
  const size_t SZ_H    = (size_t)T_SEQ * HIDN * 4;      // 33,554,432
  const size_t SZ_UV   = (size_t)T_SEQ * INTER * 2;     // 58,720,256

  __bf16* xn1    = (__bf16*)(ws);
  __bf16* qkv    = (__bf16*)(ws + SZ_XN);
  __bf16* q_r    = (__bf16*)(ws + SZ_XN + SZ_QKV);
  __bf16* ubuf   = (__bf16*)(ws);                      // overlays xn1|qkv|q_r (exactly 58,720,256)
  __bf16* k_r    = (__bf16*)(ws + SZ_UV);
  __bf16* attn_o = (__bf16*)(ws + SZ_UV + SZ_KR);
  float*  hbuf   = (float*) (ws + SZ_UV + SZ_KR + SZ_XN);
  __bf16* xn2    = (__bf16*)(ws + SZ_UV + SZ_KR + SZ_XN + SZ_H);
  __bf16* vbuf   = (__bf16*)(ws + SZ_UV + SZ_KR + SZ_XN + SZ_H + SZ_XN);
  __bf16* gbuf   = ubuf;                               // silu_mul in-place

  rmsnorm_kernel<<<T_SEQ, 256, 0, stream>>>(hidden, anw, xn1);
  gemm_bt_kernel<1><<<dim3(QKV_N / 128, T_SEQ / 128), 256, 0, stream>>>(
      xn1, wqkv, qkv, nullptr, T_SEQ, QKV_N, HIDN);
  rope_kernel<<<T_SEQ, 256, 0, stream>>>(qkv, q_r, k_r);
  attn_kernel<<<dim3(T_SEQ / 64, NH), 256, 0, stream>>>(q_r, k_r, qkv, attn_o);
  gemm_bt_kernel<2><<<dim3(HIDN / 128, T_SEQ / 128), 256, 0, stream>>>(
      attn_o, wo, hbuf, hidden, T_SEQ, HIDN, HIDN);
  rmsnorm_kernel<<<T_SEQ, 256, 0, stream>>>(hbuf, fnw, xn2);
  gemm_bt_kernel<1><<<dim3(INTER / 128, T_SEQ / 128), 256, 0, stream>>>(
      xn2, w1, ubuf, nullptr, T_SEQ, INTER, HIDN);
  gemm_bt_kernel<1><<<dim3(INTER / 128, T_SEQ / 128), 256, 0, stream>>>(
      xn2, w3, vbuf, nullptr, T_SEQ, INTER, HIDN);
  silu_mul_kernel<<<2048, 256, 0, stream>>>(ubuf, vbuf, gbuf, (long)T_SEQ * INTER);
  gemm_bt_kernel<2><<<dim3(HIDN / 128, T_SEQ / 128), 256, 0, stream>>>(
      gbuf, w2, (float*)d_out, hbuf, T_SEQ, HIDN, INTER);
}

// Round 2
// 1640.514 us; speedup vs baseline: 1.3727x; 1.3727x over previous
//
#include <hip/hip_runtime.h>
#include <stdint.h>

#define T_SEQ 2048
#define HIDN  4096
#define NH    32
#define NKV   8
#define DH    128
#define INTER 14336
#define QKV_N 6144   /* (32+16)*128 */
#define EPSR  1e-5f
#define SCALE 0.08838834764831845f  /* 1/sqrt(128) */

typedef __bf16 bf16x8 __attribute__((ext_vector_type(8)));
typedef float  f32x4  __attribute__((ext_vector_type(4)));

__device__ __forceinline__ f32x4 mfma16(bf16x8 a, bf16x8 b, f32x4 c) {
  return __builtin_amdgcn_mfma_f32_16x16x32_bf16(a, b, c, 0, 0, 0);
}

__device__ __forceinline__ void glds16(const void* g, void* l) {
  __builtin_amdgcn_global_load_lds(
      (__attribute__((address_space(1))) void*)g,
      (__attribute__((address_space(3))) void*)l,
      16, 0, 0);
}

// ---------------- fp32 -> bf16 convert (weights) ----------------
__global__ __launch_bounds__(256) void cvt_bf16_kernel(
    const float* __restrict__ src, __bf16* __restrict__ dst, long n) {
  long stride = (long)gridDim.x * 256 * 8;
  for (long i = ((long)blockIdx.x * 256 + threadIdx.x) * 8; i < n; i += stride) {
    float4 a = *(const float4*)(src + i);
    float4 b = *(const float4*)(src + i + 4);
    bf16x8 o;
    o[0]=(__bf16)a.x; o[1]=(__bf16)a.y; o[2]=(__bf16)a.z; o[3]=(__bf16)a.w;
    o[4]=(__bf16)b.x; o[5]=(__bf16)b.y; o[6]=(__bf16)b.z; o[7]=(__bf16)b.w;
    *(bf16x8*)(dst + i) = o;
  }
}

// ---------------- RMSNorm: fp32 in -> bf16 out ----------------
__global__ __launch_bounds__(256) void rmsnorm_kernel(
    const float* __restrict__ x, const float* __restrict__ w,
    __bf16* __restrict__ y) {
  const int row = blockIdx.x, tid = threadIdx.x;
  const float* xr = x + (size_t)row * HIDN + tid * 16;
  float4 v0 = ((const float4*)xr)[0];
  float4 v1 = ((const float4*)xr)[1];
  float4 v2 = ((const float4*)xr)[2];
  float4 v3 = ((const float4*)xr)[3];
  float ss = v0.x*v0.x + v0.y*v0.y + v0.z*v0.z + v0.w*v0.w
           + v1.x*v1.x + v1.y*v1.y + v1.z*v1.z + v1.w*v1.w
           + v2.x*v2.x + v2.y*v2.y + v2.z*v2.z + v2.w*v2.w
           + v3.x*v3.x + v3.y*v3.y + v3.z*v3.z + v3.w*v3.w;
  #pragma unroll
  for (int off = 32; off >= 1; off >>= 1) ss += __shfl_xor(ss, off, 64);
  __shared__ float red[4];
  if ((tid & 63) == 0) red[tid >> 6] = ss;
  __syncthreads();
  float rn = rsqrtf((red[0] + red[1] + red[2] + red[3]) * (1.0f / HIDN) + EPSR);
  const float* wr = w + tid * 16;
  float4 w0 = ((const float4*)wr)[0];
  float4 w1v = ((const float4*)wr)[1];
  float4 w2v = ((const float4*)wr)[2];
  float4 w3v = ((const float4*)wr)[3];
  bf16x8 o0, o1;
  o0[0]=(__bf16)(v0.x*rn*w0.x);  o0[1]=(__bf16)(v0.y*rn*w0.y);
  o0[2]=(__bf16)(v0.z*rn*w0.z);  o0[3]=(__bf16)(v0.w*rn*w0.w);
  o0[4]=(__bf16)(v1.x*rn*w1v.x); o0[5]=(__bf16)(v1.y*rn*w1v.y);
  o0[6]=(__bf16)(v1.z*rn*w1v.z); o0[7]=(__bf16)(v1.w*rn*w1v.w);
  o1[0]=(__bf16)(v2.x*rn*w2v.x); o1[1]=(__bf16)(v2.y*rn*w2v.y);
  o1[2]=(__bf16)(v2.z*rn*w2v.z); o1[3]=(__bf16)(v2.w*rn*w2v.w);
  o1[4]=(__bf16)(v3.x*rn*w3v.x); o1[5]=(__bf16)(v3.y*rn*w3v.y);
  o1[6]=(__bf16)(v3.z*rn*w3v.z); o1[7]=(__bf16)(v3.w*rn*w3v.w);
  __bf16* yo = y + (size_t)row * HIDN + tid * 16;
  *(bf16x8*)(yo)     = o0;
  *(bf16x8*)(yo + 8) = o1;
}

// ============ NEW GEMM: C[M,N] = A[M,K](bf16) * B[N,K](bf16)^T ============
// 128x128 tile, BK=64, both tiles via global_load_lds w/ XOR swizzle (row&7)<<4.
// EPI: 0 = write f32, 1 = write bf16, 2 = write f32 + resid
template<int EPI>
__global__ __launch_bounds__(256) void gemm_bb_kernel(
    const __bf16* __restrict__ A, const __bf16* __restrict__ B,
    void* __restrict__ Cout, const float* __restrict__ resid,
    int M, int N, int Kd) {
  __shared__ __align__(16) __bf16 As[128 * 64];
  __shared__ __align__(16) __bf16 Bs[128 * 64];
  const int tid = threadIdx.x;
  const int lane = tid & 63;
  const int wv = tid >> 6;
  const int wm = wv >> 1, wn = wv & 1;

  // bijective XCD swizzle (nwg % 8 == 0 for all our grids), then
  // 16 consecutive swz-ids (one XCD chunk) share one B panel.
  int nwg = gridDim.x * gridDim.y;
  int orig = blockIdx.y * gridDim.x + blockIdx.x;
  int cpx = nwg >> 3;
  int swz = (orig & 7) * cpx + (orig >> 3);
  int by = swz % gridDim.y;
  int bx = swz / gridDim.y;
  const int m0 = by * 128, n0 = bx * 128;

  f32x4 acc[4][4] = {};

  // precompute staging addresses (8 chunks of 16B per thread per K-tile)
  const char* asrc[4]; char* adst[4];
  const char* bsrc[4]; char* bdst[4];
  #pragma unroll
  for (int it = 0; it < 4; it++) {
    int idx = it * 256 + tid;          // 0..1023 -> As
    int row = idx >> 3;
    int cb = ((idx & 7) * 16) ^ ((row & 7) << 4);
    asrc[it] = (const char*)(A + (size_t)(m0 + row) * Kd) + cb;
    adst[it] = (char*)As + idx * 16;
    bsrc[it] = (const char*)(B + (size_t)(n0 + row) * Kd) + cb;
    bdst[it] = (char*)Bs + idx * 16;
  }

  for (int k0 = 0; k0 < Kd; k0 += 64) {
    __syncthreads();
    #pragma unroll
    for (int it = 0; it < 4; it++) glds16(asrc[it] + (size_t)k0 * 2, adst[it]);
    #pragma unroll
    for (int it = 0; it < 4; it++) glds16(bsrc[it] + (size_t)k0 * 2, bdst[it]);
    __syncthreads();
    #pragma unroll
    for (int ks = 0; ks < 2; ks++) {
      bf16x8 af[4], bfr[4];
      #pragma unroll
      for (int t2 = 0; t2 < 4; t2++) {
        int ar = wm * 64 + t2 * 16 + (lane & 15);
        int acb = (ks * 64 + ((lane >> 4) << 4)) ^ ((ar & 7) << 4);
        af[t2] = *(const bf16x8*)((char*)As + ar * 128 + acb);
        int br = wn * 64 + t2 * 16 + (lane & 15);
        int bcb = (ks * 64 + ((lane >> 4) << 4)) ^ ((br & 7) << 4);
        bfr[t2] = *(const bf16x8*)((char*)Bs + br * 128 + bcb);
      }
      #pragma unroll
      for (int mt = 0; mt < 4; mt++)
        #pragma unroll
        for (int nt = 0; nt < 4; nt++)
          acc[mt][nt] = mfma16(af[mt], bfr[nt], acc[mt][nt]);
    }
  }

  const int rbase = m0 + wm * 64 + ((lane >> 4) << 2);
  const int cbase = n0 + wn * 64 + (lane & 15);
  #pragma unroll
  for (int mt = 0; mt < 4; mt++) {
    #pragma unroll
    for (int r = 0; r < 4; r++) {
      int rr = rbase + mt * 16 + r;
      #pragma unroll
      for (int nt = 0; nt < 4; nt++) {
        int cc = cbase + nt * 16;
        size_t ix = (size_t)rr * N + cc;
        float val = acc[mt][nt][r];
        if (EPI == 0)      ((float*)Cout)[ix] = val;
        else if (EPI == 1) ((__bf16*)Cout)[ix] = (__bf16)val;
        else               ((float*)Cout)[ix] = val + resid[ix];
      }
    }
  }
}

// ======== FALLBACK GEMM (fp32 B), used only if ws too small ========
template<int EPI>
__global__ __launch_bounds__(256) void gemm_bt_kernel(
    const __bf16* __restrict__ A, const float* __restrict__ B,
    void* __restrict__ Cout, const float* __restrict__ resid,
    int M, int N, int Kd) {
  __shared__ __align__(16) __bf16 As[128 * 32];
  __shared__ __align__(16) __bf16 Bs[128 * 32];
  const int tid = threadIdx.x;
  const int lane = tid & 63;
  const int wv = tid >> 6;
  const int wm = wv >> 1, wn = wv & 1;
  int lin = blockIdx.y * gridDim.x + blockIdx.x;
  int gy = gridDim.y;
  int by = lin % gy, bx = lin / gy;
  const int m0 = by * 128, n0 = bx * 128;
  f32x4 acc[4][4] = {};
  const int brow = tid >> 1;
  const int bhalf = (tid & 1) * 16;
  const float* bsrc = B + (size_t)(n0 + brow) * Kd + bhalf;
  char* bdst0 = (char*)Bs + brow * 64 + ((bhalf * 2)      ^ ((brow & 3) << 4));
  char* bdst1 = (char*)Bs + brow * 64 + ((bhalf * 2 + 16) ^ ((brow & 3) << 4));
  for (int k0 = 0; k0 < Kd; k0 += 32) {
    __syncthreads();
    #pragma unroll
    for (int i = 0; i < 2; i++) {
      int idx = i * 256 + tid;
      int row = idx >> 2;
      int cb = ((idx & 3) * 16) ^ ((row & 3) << 4);
      glds16((const char*)(A + (size_t)(m0 + row) * Kd + k0) + cb,
             (char*)As + idx * 16);
    }
    {
      const float* bp = bsrc + k0;
      float4 f0 = ((const float4*)bp)[0];
      float4 f1 = ((const float4*)bp)[1];
      float4 f2 = ((const float4*)bp)[2];
      float4 f3 = ((const float4*)bp)[3];
      bf16x8 p0, p1;
      p0[0]=(__bf16)f0.x; p0[1]=(__bf16)f0.y; p0[2]=(__bf16)f0.z; p0[3]=(__bf16)f0.w;
      p0[4]=(__bf16)f1.x; p0[5]=(__bf16)f1.y; p0[6]=(__bf16)f1.z; p0[7]=(__bf16)f1.w;
      p1[0]=(__bf16)f2.x; p1[1]=(__bf16)f2.y; p1[2]=(__bf16)f2.z; p1[3]=(__bf16)f2.w;
      p1[4]=(__bf16)f3.x; p1[5]=(__bf16)f3.y; p1[6]=(__bf16)f3.z; p1[7]=(__bf16)f3.w;
      *(bf16x8*)bdst0 = p0;
      *(bf16x8*)bdst1 = p1;
    }
    __syncthreads();
    bf16x8 af[4], bfr[4];
    #pragma unroll
    for (int t2 = 0; t2 < 4; t2++) {
      int ar = wm * 64 + t2 * 16 + (lane & 15);
      af[t2] = *(const bf16x8*)((char*)As + ar * 64 + ((((lane >> 4) * 16)) ^ ((ar & 3) << 4)));
      int br = wn * 64 + t2 * 16 + (lane & 15);
      bfr[t2] = *(const bf16x8*)((char*)Bs + br * 64 + ((((lane >> 4) * 16)) ^ ((br & 3) << 4)));
    }
    #pragma unroll
    for (int mt = 0; mt < 4; mt++)
      #pragma unroll
      for (int nt = 0; nt < 4; nt++)
        acc[mt][nt] = mfma16(af[mt], bfr[nt], acc[mt][nt]);
  }
  const int rbase = m0 + wm * 64 + ((lane >> 4) << 2);
  const int cbase = n0 + wn * 64 + (lane & 15);
  #pragma unroll
  for (int mt = 0; mt < 4; mt++) {
    #pragma unroll
    for (int r = 0; r < 4; r++) {
      int rr = rbase + mt * 16 + r;
      #pragma unroll
      for (int nt = 0; nt < 4; nt++) {
        int cc = cbase + nt * 16;
        size_t ix = (size_t)rr * N + cc;
        float val = acc[mt][nt][r];
        if (EPI == 0)      ((float*)Cout)[ix] = val;
        else if (EPI == 1) ((__bf16*)Cout)[ix] = (__bf16)val;
        else               ((float*)Cout)[ix] = val + resid[ix];
      }
    }
  }
}

// ---------------- RoPE: qkv(bf16) -> q_r, k_r (bf16) ----------------
__global__ __launch_bounds__(256) void rope_kernel(
    const __bf16* __restrict__ qkv, __bf16* __restrict__ q_r,
    __bf16* __restrict__ k_r) {
  const int t = blockIdx.x, tid = threadIdx.x;
  __shared__ float cs[64], sn[64];
  if (tid < 64) {
    float inv = exp2f(-(float)tid * (19.931568569324174f / 64.0f)); // theta=1e6
    float f = (float)t * inv;
    cs[tid] = cosf(f);
    sn[tid] = sinf(f);
  }
  __syncthreads();
  const __bf16* row = qkv + (size_t)t * QKV_N;
  for (int it = tid; it < 40 * 64; it += 256) {
    int hh = it >> 6, i = it & 63;
    float x1 = (float)row[hh * 128 + i];
    float x2 = (float)row[hh * 128 + 64 + i];
    float c = cs[i], s = sn[i];
    float o1 = x1 * c - x2 * s;
    float o2 = x2 * c + x1 * s;
    if (hh < NH) {
      __bf16* qo = q_r + (size_t)t * HIDN + hh * 128;
      qo[i] = (__bf16)o1;
      qo[64 + i] = (__bf16)o2;
    } else {
      __bf16* ko = k_r + (size_t)t * (NKV * DH) + (hh - NH) * 128;
      ko[i] = (__bf16)o1;
      ko[64 + i] = (__bf16)o2;
    }
  }
}

// ---------------- Flash attention (causal, GQA) ----------------
__global__ __launch_bounds__(256) void attn_kernel(
    const __bf16* __restrict__ q_r, const __bf16* __restrict__ k_r,
    const __bf16* __restrict__ qkv, __bf16* __restrict__ attn_o) {
  __shared__ __align__(16) __bf16 Ks[32 * 128];
  __shared__ __align__(16) __bf16 Vt[128][40];
  __shared__ __align__(16) __bf16 Pl[4][16][40];

  const int tid = threadIdx.x;
  const int lane = tid & 63, wv = tid >> 6;
  const int qt = blockIdx.x, h = blockIdx.y;
  const int kh = h >> 2;  // G = 4
  const int q0b = qt * 64;
  const int q0w = q0b + wv * 16;

  bf16x8 qf[4];
  {
    const __bf16* qp = q_r + (size_t)(q0w + (lane & 15)) * HIDN + h * DH + ((lane >> 4) << 3);
    #pragma unroll
    for (int kk = 0; kk < 4; kk++) qf[kk] = *(const bf16x8*)(qp + kk * 32);
  }

  f32x4 o[8] = {};
  float mrun[4] = {-1e30f, -1e30f, -1e30f, -1e30f};
  float lrun[4] = {0.f, 0.f, 0.f, 0.f};

  const int kv_end = q0b + 64;
  for (int kv0 = 0; kv0 < kv_end; kv0 += 32) {
    __syncthreads();
    #pragma unroll
    for (int i = 0; i < 2; i++) {
      int idx = i * 256 + tid;
      int row = idx >> 4;
      int cb = ((idx & 15) * 16) ^ ((row & 7) << 4);
      glds16((const char*)(k_r + (size_t)(kv0 + row) * (NKV * DH) + kh * DH) + cb,
             (char*)Ks + idx * 16);
    }
    {
      int d = tid & 127;
      int kvh = (tid >> 7) << 4;
      const __bf16* vp = qkv + (size_t)(kv0 + kvh) * QKV_N + (NH + NKV) * DH + kh * DH + d;
      #pragma unroll
      for (int j = 0; j < 16; j++) Vt[d][kvh + j] = vp[(size_t)j * QKV_N];
    }
    __syncthreads();

    if (q0w + 15 >= kv0) {
      f32x4 s[2] = {};
      #pragma unroll
      for (int kk = 0; kk < 4; kk++) {
        #pragma unroll
        for (int jt = 0; jt < 2; jt++) {
          int row = jt * 16 + (lane & 15);
          int cb = (kk * 64 + ((lane >> 4) << 4)) ^ ((row & 7) << 4);
          bf16x8 kf = *(const bf16x8*)((char*)Ks + row * 256 + cb);
          s[jt] = mfma16(qf[kk], kf, s[jt]);
        }
      }
      float p0[4], p1[4], mx[4];
      const bool need_mask = (kv0 + 31) > q0w;
      #pragma unroll
      for (int r = 0; r < 4; r++) {
        float a = s[0][r] * SCALE, b = s[1][r] * SCALE;
        if (need_mask) {
          int qpos = q0w + ((lane >> 4) << 2) + r;
          int kva = kv0 + (lane & 15);
          if (kva > qpos) a = -1e30f;
          if (kva + 16 > qpos) b = -1e30f;
        }
        p0[r] = a; p1[r] = b;
        mx[r] = fmaxf(a, b);
      }
      #pragma unroll
      for (int r = 0; r < 4; r++) {
        #pragma unroll
        for (int off = 1; off < 16; off <<= 1)
          mx[r] = fmaxf(mx[r], __shfl_xor(mx[r], off, 64));
        float mn = fmaxf(mrun[r], mx[r]);
        float corr = __expf(mrun[r] - mn);
        mrun[r] = mn;
        p0[r] = __expf(p0[r] - mn);
        p1[r] = __expf(p1[r] - mn);
        float ps = p0[r] + p1[r];
        #pragma unroll
        for (int off = 1; off < 16; off <<= 1) ps += __shfl_xor(ps, off, 64);
        lrun[r] = lrun[r] * corr + ps;
        #pragma unroll
        for (int nt = 0; nt < 8; nt++) o[nt][r] *= corr;
        int prow = ((lane >> 4) << 2) + r;
        Pl[wv][prow][lane & 15]      = (__bf16)p0[r];
        Pl[wv][prow][16 + (lane & 15)] = (__bf16)p1[r];
      }
      bf16x8 pf = *(const bf16x8*)&Pl[wv][lane & 15][(lane >> 4) << 3];
      #pragma unroll
      for (int nt = 0; nt < 8; nt++) {
        bf16x8 vf = *(const bf16x8*)&Vt[nt * 16 + (lane & 15)][(lane >> 4) << 3];
        o[nt] = mfma16(pf, vf, o[nt]);
      }
    }
  }

  #pragma unroll
  for (int nt = 0; nt < 8; nt++) {
    #pragma unroll
    for (int r = 0; r < 4; r++) {
      int qrow = q0w + ((lane >> 4) << 2) + r;
      int d = nt * 16 + (lane & 15);
      attn_o[(size_t)qrow * HIDN + h * DH + d] = (__bf16)(o[nt][r] / lrun[r]);
    }
  }
}

// ---------------- SwiGLU elementwise: g = silu(u) * v ----------------
__global__ __launch_bounds__(256) void silu_mul_kernel(
    const __bf16* __restrict__ u, const __bf16* __restrict__ v,
    __bf16* __restrict__ g, long n) {
  long stride = (long)gridDim.x * 256 * 8;
  for (long i = ((long)blockIdx.x * 256 + threadIdx.x) * 8; i < n; i += stride) {
    bf16x8 uu = *(const bf16x8*)(u + i);
    bf16x8 vv = *(const bf16x8*)(v + i);
    bf16x8 gg;
    #pragma unroll
    for (int j = 0; j < 8; j++) {
      float x = (float)uu[j];
      float y = (float)vv[j];
      float sl = x / (1.0f + __expf(-x));
      gg[j] = (__bf16)(sl * y);
    }
    *(bf16x8*)(g + i) = gg;
  }
}

extern "C" void kernel_launch(void* const* d_in, const int* in_sizes, int n_in,
                              void* d_out, int out_size, void* d_ws, size_t ws_size,
                              hipStream_t stream) {
  const float* hidden = (const float*)d_in[0];
  const float* wqkv = (const float*)d_in[2];
  const float* wo   = (const float*)d_in[3];
  const float* w1   = (const float*)d_in[4];
  const float* w3   = (const float*)d_in[5];
  const float* w2   = (const float*)d_in[6];
  const float* anw  = (const float*)d_in[7];
  const float* fnw  = (const float*)d_in[8];

  char* ws = (char*)d_ws;
  const size_t SZ_XN   = (size_t)T_SEQ * HIDN * 2;      // 16,777,216
  const size_t SZ_QKV  = (size_t)T_SEQ * QKV_N * 2;     // 25,165,824
  const size_t SZ_KR   = (size_t)T_SEQ * NKV * DH * 2;  //  4,194,304
  const size_t SZ_H    = (size_t)T_SEQ * HIDN * 4;      // 33,554,432
  const size_t SZ_UV   = (size_t)T_SEQ * INTER * 2;     // 58,720,256
  const size_t ACT_TOTAL = SZ_UV + SZ_KR + SZ_XN + SZ_H + SZ_XN + SZ_UV;

  const size_t W_QKV = (size_t)QKV_N * HIDN * 2;   // 50,331,648
  const size_t W_O   = (size_t)HIDN * HIDN * 2;    // 33,554,432
  const size_t W_I   = (size_t)INTER * HIDN * 2;   // 117,440,512
  const size_t W_TOTAL = W_QKV + W_O + 3 * W_I;    // 436,207,616

  const bool big_ws = ws_size >= W_TOTAL + ACT_TOTAL;
  char* act = big_ws ? (ws + W_TOTAL) : ws;

  __bf16* xn1    = (__bf16*)(act);
  __bf16* qkv    = (__bf16*)(act + SZ_XN);
  __bf16* q_r    = (__bf16*)(act + SZ_XN + SZ_QKV);
  __bf16* ubuf   = (__bf16*)(act);                      // overlays xn1|qkv|q_r
  __bf16* k_r    = (__bf16*)(act + SZ_UV);
  __bf16* attn_o = (__bf16*)(act + SZ_UV + SZ_KR);
  float*  hbuf   = (float*) (act + SZ_UV + SZ_KR + SZ_XN);
  __bf16* xn2    = (__bf16*)(act + SZ_UV + SZ_KR + SZ_XN + SZ_H);
  __bf16* vbuf   = (__bf16*)(act + SZ_UV + SZ_KR + SZ_XN + SZ_H + SZ_XN);
  __bf16* gbuf   = ubuf;

  if (big_ws) {
    __bf16* wqkv_b = (__bf16*)(ws);
    __bf16* wo_b   = (__bf16*)(ws + W_QKV);
    __bf16* w1_b   = (__bf16*)(ws + W_QKV + W_O);
    __bf16* w3_b   = (__bf16*)(ws + W_QKV + W_O + W_I);
    __bf16* w2_b   = (__bf16*)(ws + W_QKV + W_O + 2 * W_I);

    cvt_bf16_kernel<<<2048, 256, 0, stream>>>(wqkv, wqkv_b, (long)QKV_N * HIDN);
    cvt_bf16_kernel<<<2048, 256, 0, stream>>>(wo,   wo_b,   (long)HIDN * HIDN);
    cvt_bf16_kernel<<<2048, 256, 0, stream>>>(w1,   w1_b,   (long)INTER * HIDN);
    cvt_bf16_kernel<<<2048, 256, 0, stream>>>(w3,   w3_b,   (long)INTER * HIDN);
    cvt_bf16_kernel<<<2048, 256, 0, stream>>>(w2,   w2_b,   (long)HIDN * INTER);

    rmsnorm_kernel<<<T_SEQ, 256, 0, stream>>>(hidden, anw, xn1);
    gemm_bb_kernel<1><<<dim3(QKV_N / 128, T_SEQ / 128), 256, 0, stream>>>(
        xn1, wqkv_b, qkv, nullptr, T_SEQ, QKV_N, HIDN);
    rope_kernel<<<T_SEQ, 256, 0, stream>>>(qkv, q_r, k_r);
    attn_kernel<<<dim3(T_SEQ / 64, NH), 256, 0, stream>>>(q_r, k_r, qkv, attn_o);
    gemm_bb_kernel<2><<<dim3(HIDN / 128, T_SEQ / 128), 256, 0, stream>>>(
        attn_o, wo_b, hbuf, hidden, T_SEQ, HIDN, HIDN);
    rmsnorm_kernel<<<T_SEQ, 256, 0, stream>>>(hbuf, fnw, xn2);
    gemm_bb_kernel<1><<<dim3(INTER / 128, T_SEQ / 128), 256, 0, stream>>>(
        xn2, w1_b, ubuf, nullptr, T_SEQ, INTER, HIDN);
    gemm_bb_kernel<1><<<dim3(INTER / 128, T_SEQ / 128), 256, 0, stream>>>(
        xn2, w3_b, vbuf, nullptr, T_SEQ, INTER, HIDN);
    silu_mul_kernel<<<2048, 256, 0, stream>>>(ubuf, vbuf, gbuf, (long)T_SEQ * INTER);
    gemm_bb_kernel<2><<<dim3(HIDN / 128, T_SEQ / 128), 256, 0, stream>>>(
        gbuf, w2_b, (float*)d_out, hbuf, T_SEQ, HIDN, INTER);
  } else {
    rmsnorm_kernel<<<T_SEQ, 256, 0, stream>>>(hidden, anw, xn1);
    gemm_bt_kernel<1><<<dim3(QKV_N / 128, T_SEQ / 128), 256, 0, stream>>>(
        xn1, wqkv, qkv, nullptr, T_SEQ, QKV_N, HIDN);
    rope_kernel<<<T_SEQ, 256, 0, stream>>>(qkv, q_r, k_r);
    attn_kernel<<<dim3(T_SEQ / 64, NH), 256, 0, stream>>>(q_r, k_r, qkv, attn_o);
    gemm_bt_kernel<2><<<dim3(HIDN / 128, T_SEQ / 128), 256, 0, stream>>>(
        attn_o, wo, hbuf, hidden, T_SEQ, HIDN, HIDN);
    rmsnorm_kernel<<<T_SEQ, 256, 0, stream>>>(hbuf, fnw, xn2);
    gemm_bt_kernel<1><<<dim3(INTER / 128, T_SEQ / 128), 256, 0, stream>>>(
        xn2, w1, ubuf, nullptr, T_SEQ, INTER, HIDN);
    gemm_bt_kernel<1><<<dim3(INTER / 128, T_SEQ / 128), 256, 0, stream>>>(
        xn2, w3, vbuf, nullptr, T_SEQ, INTER, HIDN);
    silu_mul_kernel<<<2048, 256, 0, stream>>>(ubuf, vbuf, gbuf, (long)T_SEQ * INTER);
    gemm_bt_kernel<2><<<dim3(HIDN / 128, T_SEQ / 128), 256, 0, stream>>>(
        gbuf, w2, (float*)d_out, hbuf, T_SEQ, HIDN, INTER);
  }
}

// Round 3
// 1413.505 us; speedup vs baseline: 1.5932x; 1.1606x over previous
//
#include <hip/hip_runtime.h>
#include <stdint.h>

#define T_SEQ 2048
#define HIDN  4096
#define NH    32
#define NKV   8
#define DH    128
#define INTER 14336
#define QKV_N 6144   /* (32+16)*128 */
#define EPSR  1e-5f
#define SCALE 0.08838834764831845f  /* 1/sqrt(128) */

typedef __bf16 bf16x8 __attribute__((ext_vector_type(8)));
typedef float  f32x4  __attribute__((ext_vector_type(4)));

__device__ __forceinline__ f32x4 mfma16(bf16x8 a, bf16x8 b, f32x4 c) {
  return __builtin_amdgcn_mfma_f32_16x16x32_bf16(a, b, c, 0, 0, 0);
}

__device__ __forceinline__ void glds16(const void* g, void* l) {
  __builtin_amdgcn_global_load_lds(
      (__attribute__((address_space(1))) void*)g,
      (__attribute__((address_space(3))) void*)l,
      16, 0, 0);
}

// ---------------- fp32 -> bf16 convert (weights) ----------------
__global__ __launch_bounds__(256) void cvt_bf16_kernel(
    const float* __restrict__ src, __bf16* __restrict__ dst, long n) {
  long stride = (long)gridDim.x * 256 * 8;
  for (long i = ((long)blockIdx.x * 256 + threadIdx.x) * 8; i < n; i += stride) {
    float4 a = *(const float4*)(src + i);
    float4 b = *(const float4*)(src + i + 4);
    bf16x8 o;
    o[0]=(__bf16)a.x; o[1]=(__bf16)a.y; o[2]=(__bf16)a.z; o[3]=(__bf16)a.w;
    o[4]=(__bf16)b.x; o[5]=(__bf16)b.y; o[6]=(__bf16)b.z; o[7]=(__bf16)b.w;
    *(bf16x8*)(dst + i) = o;
  }
}

// ---------------- RMSNorm: fp32 in -> bf16 out ----------------
__global__ __launch_bounds__(256) void rmsnorm_kernel(
    const float* __restrict__ x, const float* __restrict__ w,
    __bf16* __restrict__ y) {
  const int row = blockIdx.x, tid = threadIdx.x;
  const float* xr = x + (size_t)row * HIDN + tid * 16;
  float4 v0 = ((const float4*)xr)[0];
  float4 v1 = ((const float4*)xr)[1];
  float4 v2 = ((const float4*)xr)[2];
  float4 v3 = ((const float4*)xr)[3];
  float ss = v0.x*v0.x + v0.y*v0.y + v0.z*v0.z + v0.w*v0.w
           + v1.x*v1.x + v1.y*v1.y + v1.z*v1.z + v1.w*v1.w
           + v2.x*v2.x + v2.y*v2.y + v2.z*v2.z + v2.w*v2.w
           + v3.x*v3.x + v3.y*v3.y + v3.z*v3.z + v3.w*v3.w;
  #pragma unroll
  for (int off = 32; off >= 1; off >>= 1) ss += __shfl_xor(ss, off, 64);
  __shared__ float red[4];
  if ((tid & 63) == 0) red[tid >> 6] = ss;
  __syncthreads();
  float rn = rsqrtf((red[0] + red[1] + red[2] + red[3]) * (1.0f / HIDN) + EPSR);
  const float* wr = w + tid * 16;
  float4 w0 = ((const float4*)wr)[0];
  float4 w1v = ((const float4*)wr)[1];
  float4 w2v = ((const float4*)wr)[2];
  float4 w3v = ((const float4*)wr)[3];
  bf16x8 o0, o1;
  o0[0]=(__bf16)(v0.x*rn*w0.x);  o0[1]=(__bf16)(v0.y*rn*w0.y);
  o0[2]=(__bf16)(v0.z*rn*w0.z);  o0[3]=(__bf16)(v0.w*rn*w0.w);
  o0[4]=(__bf16)(v1.x*rn*w1v.x); o0[5]=(__bf16)(v1.y*rn*w1v.y);
  o0[6]=(__bf16)(v1.z*rn*w1v.z); o0[7]=(__bf16)(v1.w*rn*w1v.w);
  o1[0]=(__bf16)(v2.x*rn*w2v.x); o1[1]=(__bf16)(v2.y*rn*w2v.y);
  o1[2]=(__bf16)(v2.z*rn*w2v.z); o1[3]=(__bf16)(v2.w*rn*w2v.w);
  o1[4]=(__bf16)(v3.x*rn*w3v.x); o1[5]=(__bf16)(v3.y*rn*w3v.y);
  o1[6]=(__bf16)(v3.z*rn*w3v.z); o1[7]=(__bf16)(v3.w*rn*w3v.w);
  __bf16* yo = y + (size_t)row * HIDN + tid * 16;
  *(bf16x8*)(yo)     = o0;
  *(bf16x8*)(yo + 8) = o1;
}

// ============ 256x256 deep-pipelined GEMM: C = A[M,K] * B[N,K]^T (bf16) ============
// 512 thr / 8 waves (2Mx4N), wave tile 128x64, BK=32, 5-deep LDS circular buffer
// (5 x 32KB = 160KB dynamic LDS), ONE raw s_barrier per K-tile, counted vmcnt(12).
// LDS layout per tile: A[256 rows][4 slots of 16B], slot permuted by (row>>1)&3
// (inverse-permuted global source keeps glds dest linear; read applies same XOR).
// EPI: 0 = write f32 partial at Cout + z*M*N, 1 = write bf16
template<int EPI>
__global__ __launch_bounds__(512, 2) void gemm256_kernel(
    const __bf16* __restrict__ A, const __bf16* __restrict__ B,
    void* __restrict__ Cout, int M, int N, int Kfull, int KZ) {
  extern __shared__ __align__(16) char smem[];
  const int tid = threadIdx.x;
  const int lane = tid & 63;
  const int wv = tid >> 6;        // 0..7
  const int wm = wv >> 2;         // 0..1
  const int wn = wv & 3;          // 0..3
  const int lr = lane & 15, q = lane >> 4;

  const int gx = gridDim.x, gy = gridDim.y;
  const int nwg = gx * gy;                 // multiple of 8 for all our shapes
  const int orig = blockIdx.y * gx + blockIdx.x;
  const int cpx = nwg >> 3;
  const int swz = (orig & 7) * cpx + (orig >> 3);
  const int by = swz % gy, bx = swz / gy;
  const int m0 = by * 256, n0 = bx * 256;
  const int kbase = blockIdx.z * KZ;
  const int NT = KZ >> 5;                  // K-tiles of 32

  // per-thread staging sources (pre-inverse-swizzled) and LDS dests (linear)
  const char* aS[2]; const char* bS[2]; int Lds[2];
  #pragma unroll
  for (int j = 0; j < 2; j++) {
    int L = j * 512 + tid;                 // 16B unit index, 0..1023
    int row = L >> 2;
    int s = (L & 3) ^ ((row >> 1) & 3);    // logical k-slot stored at this unit
    aS[j] = (const char*)(A + (size_t)(m0 + row) * Kfull + kbase + s * 8);
    bS[j] = (const char*)(B + (size_t)(n0 + row) * Kfull + kbase + s * 8);
    Lds[j] = L * 16;
  }

  // fragment read offsets (slot-XOR matches staging permutation)
  const int sA = q ^ ((lr >> 1) & 3);
  int aoff[8], boff[4];
  #pragma unroll
  for (int mt = 0; mt < 8; mt++) aoff[mt] = (wm * 128 + mt * 16 + lr) * 64 + sA * 16;
  #pragma unroll
  for (int nt = 0; nt < 4; nt++) boff[nt] = 16384 + (wn * 64 + nt * 16 + lr) * 64 + sA * 16;

#define STAGE_T(tile, sb) do {                                   \
    char* _b = smem + (sb) * 32768;                              \
    size_t _ko = (size_t)(tile) * 64;                            \
    glds16(aS[0] + _ko, _b + Lds[0]);                            \
    glds16(aS[1] + _ko, _b + Lds[1]);                            \
    glds16(bS[0] + _ko, _b + 16384 + Lds[0]);                    \
    glds16(bS[1] + _ko, _b + 16384 + Lds[1]);                    \
  } while (0)

#define GBODY(VMC, DOST) do {                                    \
    if (DOST) { STAGE_T(t + 3, sbufi); sbufi = (sbufi == 4) ? 0 : sbufi + 1; } \
    asm volatile("s_waitcnt vmcnt(" #VMC ")" ::: "memory");      \
    __builtin_amdgcn_s_barrier();                                \
    asm volatile("" ::: "memory");                               \
    __builtin_amdgcn_sched_barrier(0);                           \
    { const char* _bA = smem + bufi * 32768;                     \
      bf16x8 bf[4], af[8];                                       \
      _Pragma("unroll") for (int nt = 0; nt < 4; nt++)           \
        bf[nt] = *(const bf16x8*)(_bA + boff[nt]);               \
      _Pragma("unroll") for (int mt = 0; mt < 8; mt++)           \
        af[mt] = *(const bf16x8*)(_bA + aoff[mt]);               \
      __builtin_amdgcn_s_setprio(1);                             \
      _Pragma("unroll") for (int mt = 0; mt < 8; mt++)           \
        _Pragma("unroll") for (int nt = 0; nt < 4; nt++)         \
          acc[mt][nt] = mfma16(af[mt], bf[nt], acc[mt][nt]);     \
      __builtin_amdgcn_s_setprio(0); }                           \
    bufi = (bufi == 4) ? 0 : bufi + 1;                           \
  } while (0)

  f32x4 acc[8][4] = {};
  STAGE_T(0, 0); STAGE_T(1, 1); STAGE_T(2, 2);
  int bufi = 0, sbufi = 3;
  for (int t = 0; t < NT - 3; ++t) GBODY(12, true);
  { int t = 0; (void)t;
    GBODY(8, false); GBODY(4, false); GBODY(0, false); }
#undef STAGE_T
#undef GBODY

  // epilogue
  #pragma unroll
  for (int mt = 0; mt < 8; mt++) {
    #pragma unroll
    for (int r = 0; r < 4; r++) {
      int rr = m0 + wm * 128 + mt * 16 + q * 4 + r;
      #pragma unroll
      for (int nt = 0; nt < 4; nt++) {
        int cc = n0 + wn * 64 + nt * 16 + lr;
        size_t ix = (size_t)rr * N + cc;
        float val = acc[mt][nt][r];
        if (EPI == 0) ((float*)Cout)[(size_t)blockIdx.z * M * N + ix] = val;
        else          ((__bf16*)Cout)[ix] = (__bf16)val;
      }
    }
  }
}

// ---------------- split-K combine: out = p[0] + p[1] + resid ----------------
__global__ __launch_bounds__(256) void add3_kernel(
    const float* __restrict__ p, const float* __restrict__ r,
    float* __restrict__ o, long n) {
  long stride = (long)gridDim.x * 1024;
  for (long i = ((long)blockIdx.x * 256 + threadIdx.x) * 4; i < n; i += stride) {
    float4 a = *(const float4*)(p + i);
    float4 b = *(const float4*)(p + n + i);
    float4 c = *(const float4*)(r + i);
    float4 o4;
    o4.x = a.x + b.x + c.x; o4.y = a.y + b.y + c.y;
    o4.z = a.z + b.z + c.z; o4.w = a.w + b.w + c.w;
    *(float4*)(o + i) = o4;
  }
}

// ---------------- RoPE: qkv(bf16) -> q_r, k_r (bf16) ----------------
__global__ __launch_bounds__(256) void rope_kernel(
    const __bf16* __restrict__ qkv, __bf16* __restrict__ q_r,
    __bf16* __restrict__ k_r) {
  const int t = blockIdx.x, tid = threadIdx.x;
  __shared__ float cs[64], sn[64];
  if (tid < 64) {
    float inv = exp2f(-(float)tid * (19.931568569324174f / 64.0f)); // theta=1e6
    float f = (float)t * inv;
    cs[tid] = cosf(f);
    sn[tid] = sinf(f);
  }
  __syncthreads();
  const __bf16* row = qkv + (size_t)t * QKV_N;
  for (int it = tid; it < 40 * 64; it += 256) {
    int hh = it >> 6, i = it & 63;
    float x1 = (float)row[hh * 128 + i];
    float x2 = (float)row[hh * 128 + 64 + i];
    float c = cs[i], s = sn[i];
    float o1 = x1 * c - x2 * s;
    float o2 = x2 * c + x1 * s;
    if (hh < NH) {
      __bf16* qo = q_r + (size_t)t * HIDN + hh * 128;
      qo[i] = (__bf16)o1;
      qo[64 + i] = (__bf16)o2;
    } else {
      __bf16* ko = k_r + (size_t)t * (NKV * DH) + (hh - NH) * 128;
      ko[i] = (__bf16)o1;
      ko[64 + i] = (__bf16)o2;
    }
  }
}

// ---------------- Flash attention (causal, GQA) ----------------
__global__ __launch_bounds__(256) void attn_kernel(
    const __bf16* __restrict__ q_r, const __bf16* __restrict__ k_r,
    const __bf16* __restrict__ qkv, __bf16* __restrict__ attn_o) {
  __shared__ __align__(16) __bf16 Ks[32 * 128];
  __shared__ __align__(16) __bf16 Vt[128][40];
  __shared__ __align__(16) __bf16 Pl[4][16][40];

  const int tid = threadIdx.x;
  const int lane = tid & 63, wv = tid >> 6;
  const int qt = blockIdx.x, h = blockIdx.y;
  const int kh = h >> 2;  // G = 4
  const int q0b = qt * 64;
  const int q0w = q0b + wv * 16;

  bf16x8 qf[4];
  {
    const __bf16* qp = q_r + (size_t)(q0w + (lane & 15)) * HIDN + h * DH + ((lane >> 4) << 3);
    #pragma unroll
    for (int kk = 0; kk < 4; kk++) qf[kk] = *(const bf16x8*)(qp + kk * 32);
  }

  f32x4 o[8] = {};
  float mrun[4] = {-1e30f, -1e30f, -1e30f, -1e30f};
  float lrun[4] = {0.f, 0.f, 0.f, 0.f};

  const int kv_end = q0b + 64;
  for (int kv0 = 0; kv0 < kv_end; kv0 += 32) {
    __syncthreads();
    #pragma unroll
    for (int i = 0; i < 2; i++) {
      int idx = i * 256 + tid;
      int row = idx >> 4;
      int cb = ((idx & 15) * 16) ^ ((row & 7) << 4);
      glds16((const char*)(k_r + (size_t)(kv0 + row) * (NKV * DH) + kh * DH) + cb,
             (char*)Ks + idx * 16);
    }
    {
      int d = tid & 127;
      int kvh = (tid >> 7) << 4;
      const __bf16* vp = qkv + (size_t)(kv0 + kvh) * QKV_N + (NH + NKV) * DH + kh * DH + d;
      #pragma unroll
      for (int j = 0; j < 16; j++) Vt[d][kvh + j] = vp[(size_t)j * QKV_N];
    }
    __syncthreads();

    if (q0w + 15 >= kv0) {
      f32x4 s[2] = {};
      #pragma unroll
      for (int kk = 0; kk < 4; kk++) {
        #pragma unroll
        for (int jt = 0; jt < 2; jt++) {
          int row = jt * 16 + (lane & 15);
          int cb = (kk * 64 + ((lane >> 4) << 4)) ^ ((row & 7) << 4);
          bf16x8 kf = *(const bf16x8*)((char*)Ks + row * 256 + cb);
          s[jt] = mfma16(qf[kk], kf, s[jt]);
        }
      }
      float p0[4], p1[4], mx[4];
      const bool need_mask = (kv0 + 31) > q0w;
      #pragma unroll
      for (int r = 0; r < 4; r++) {
        float a = s[0][r] * SCALE, b = s[1][r] * SCALE;
        if (need_mask) {
          int qpos = q0w + ((lane >> 4) << 2) + r;
          int kva = kv0 + (lane & 15);
          if (kva > qpos) a = -1e30f;
          if (kva + 16 > qpos) b = -1e30f;
        }
        p0[r] = a; p1[r] = b;
        mx[r] = fmaxf(a, b);
      }
      #pragma unroll
      for (int r = 0; r < 4; r++) {
        #pragma unroll
        for (int off = 1; off < 16; off <<= 1)
          mx[r] = fmaxf(mx[r], __shfl_xor(mx[r], off, 64));
        float mn = fmaxf(mrun[r], mx[r]);
        float corr = __expf(mrun[r] - mn);
        mrun[r] = mn;
        p0[r] = __expf(p0[r] - mn);
        p1[r] = __expf(p1[r] - mn);
        float ps = p0[r] + p1[r];
        #pragma unroll
        for (int off = 1; off < 16; off <<= 1) ps += __shfl_xor(ps, off, 64);
        lrun[r] = lrun[r] * corr + ps;
        #pragma unroll
        for (int nt = 0; nt < 8; nt++) o[nt][r] *= corr;
        int prow = ((lane >> 4) << 2) + r;
        Pl[wv][prow][lane & 15]      = (__bf16)p0[r];
        Pl[wv][prow][16 + (lane & 15)] = (__bf16)p1[r];
      }
      bf16x8 pf = *(const bf16x8*)&Pl[wv][lane & 15][(lane >> 4) << 3];
      #pragma unroll
      for (int nt = 0; nt < 8; nt++) {
        bf16x8 vf = *(const bf16x8*)&Vt[nt * 16 + (lane & 15)][(lane >> 4) << 3];
        o[nt] = mfma16(pf, vf, o[nt]);
      }
    }
  }

  #pragma unroll
  for (int nt = 0; nt < 8; nt++) {
    #pragma unroll
    for (int r = 0; r < 4; r++) {
      int qrow = q0w + ((lane >> 4) << 2) + r;
      int d = nt * 16 + (lane & 15);
      attn_o[(size_t)qrow * HIDN + h * DH + d] = (__bf16)(o[nt][r] / lrun[r]);
    }
  }
}

// ---------------- SwiGLU elementwise: g = silu(u) * v ----------------
__global__ __launch_bounds__(256) void silu_mul_kernel(
    const __bf16* __restrict__ u, const __bf16* __restrict__ v,
    __bf16* __restrict__ g, long n) {
  long stride = (long)gridDim.x * 256 * 8;
  for (long i = ((long)blockIdx.x * 256 + threadIdx.x) * 8; i < n; i += stride) {
    bf16x8 uu = *(const bf16x8*)(u + i);
    bf16x8 vv = *(const bf16x8*)(v + i);
    bf16x8 gg;
    #pragma unroll
    for (int j = 0; j < 8; j++) {
      float x = (float)uu[j];
      float y = (float)vv[j];
      float sl = x / (1.0f + __expf(-x));
      gg[j] = (__bf16)(sl * y);
    }
    *(bf16x8*)(g + i) = gg;
  }
}

extern "C" void kernel_launch(void* const* d_in, const int* in_sizes, int n_in,
                              void* d_out, int out_size, void* d_ws, size_t ws_size,
                              hipStream_t stream) {
  const float* hidden = (const float*)d_in[0];
  const float* wqkv = (const float*)d_in[2];
  const float* wo   = (const float*)d_in[3];
  const float* w1   = (const float*)d_in[4];
  const float* w3   = (const float*)d_in[5];
  const float* w2   = (const float*)d_in[6];
  const float* anw  = (const float*)d_in[7];
  const float* fnw  = (const float*)d_in[8];

  char* ws = (char*)d_ws;
  const size_t SZ_XN   = (size_t)T_SEQ * HIDN * 2;      // 16,777,216
  const size_t SZ_QKV  = (size_t)T_SEQ * QKV_N * 2;     // 25,165,824
  const size_t SZ_KR   = (size_t)T_SEQ * NKV * DH * 2;  //  4,194,304
  const size_t SZ_H    = (size_t)T_SEQ * HIDN * 4;      // 33,554,432
  const size_t SZ_UV   = (size_t)T_SEQ * INTER * 2;     // 58,720,256

  const size_t W_QKV = (size_t)QKV_N * HIDN * 2;   // 50,331,648
  const size_t W_O   = (size_t)HIDN * HIDN * 2;    // 33,554,432
  const size_t W_I   = (size_t)INTER * HIDN * 2;   // 117,440,512
  const size_t W_TOTAL = W_QKV + W_O + 3 * W_I;    // 436,207,616

  char* act = ws + W_TOTAL;

  __bf16* xn1    = (__bf16*)(act);
  __bf16* qkv    = (__bf16*)(act + SZ_XN);
  __bf16* q_r    = (__bf16*)(act + SZ_XN + SZ_QKV);
  __bf16* ubuf   = (__bf16*)(act);                      // overlays xn1|qkv|q_r
  __bf16* k_r    = (__bf16*)(act + SZ_UV);
  __bf16* attn_o = (__bf16*)(act + SZ_UV + SZ_KR);
  float*  hbuf   = (float*) (act + SZ_UV + SZ_KR + SZ_XN);
  __bf16* xn2    = (__bf16*)(act + SZ_UV + SZ_KR + SZ_XN + SZ_H);
  __bf16* vbuf   = (__bf16*)(act + SZ_UV + SZ_KR + SZ_XN + SZ_H + SZ_XN);
  __bf16* gbuf   = ubuf;
  // split-K f32 partials (2 x 33.5 MB) overlay the xn2+vbuf region
  // (dead during O-proj; dead again during w2 after silu consumed vbuf)
  float*  pbuf   = (float*)(act + SZ_UV + SZ_KR + SZ_XN + SZ_H);

  __bf16* wqkv_b = (__bf16*)(ws);
  __bf16* wo_b   = (__bf16*)(ws + W_QKV);
  __bf16* w1_b   = (__bf16*)(ws + W_QKV + W_O);
  __bf16* w3_b   = (__bf16*)(ws + W_QKV + W_O + W_I);
  __bf16* w2_b   = (__bf16*)(ws + W_QKV + W_O + 2 * W_I);

  const int LDS_BYTES = 163840;
  hipFuncSetAttribute((const void*)gemm256_kernel<0>,
                      hipFuncAttributeMaxDynamicSharedMemorySize, LDS_BYTES);
  hipFuncSetAttribute((const void*)gemm256_kernel<1>,
                      hipFuncAttributeMaxDynamicSharedMemorySize, LDS_BYTES);

  cvt_bf16_kernel<<<2048, 256, 0, stream>>>(wqkv, wqkv_b, (long)QKV_N * HIDN);
  cvt_bf16_kernel<<<2048, 256, 0, stream>>>(wo,   wo_b,   (long)HIDN * HIDN);
  cvt_bf16_kernel<<<2048, 256, 0, stream>>>(w1,   w1_b,   (long)INTER * HIDN);
  cvt_bf16_kernel<<<2048, 256, 0, stream>>>(w3,   w3_b,   (long)INTER * HIDN);
  cvt_bf16_kernel<<<2048, 256, 0, stream>>>(w2,   w2_b,   (long)HIDN * INTER);

  rmsnorm_kernel<<<T_SEQ, 256, 0, stream>>>(hidden, anw, xn1);
  // QKV: M=2048 N=6144 K=4096, bf16 out
  gemm256_kernel<1><<<dim3(QKV_N / 256, T_SEQ / 256, 1), 512, LDS_BYTES, stream>>>(
      xn1, wqkv_b, qkv, T_SEQ, QKV_N, HIDN, HIDN);
  rope_kernel<<<T_SEQ, 256, 0, stream>>>(qkv, q_r, k_r);
  attn_kernel<<<dim3(T_SEQ / 64, NH), 256, 0, stream>>>(q_r, k_r, qkv, attn_o);
  // O-proj: split-K=2 partials, then combine with residual
  gemm256_kernel<0><<<dim3(HIDN / 256, T_SEQ / 256, 2), 512, LDS_BYTES, stream>>>(
      attn_o, wo_b, pbuf, T_SEQ, HIDN, HIDN, HIDN / 2);
  add3_kernel<<<2048, 256, 0, stream>>>(pbuf, hidden, hbuf, (long)T_SEQ * HIDN);
  rmsnorm_kernel<<<T_SEQ, 256, 0, stream>>>(hbuf, fnw, xn2);
  // W1 / W3: M=2048 N=14336 K=4096, bf16 out
  gemm256_kernel<1><<<dim3(INTER / 256, T_SEQ / 256, 1), 512, LDS_BYTES, stream>>>(
      xn2, w1_b, ubuf, T_SEQ, INTER, HIDN, HIDN);
  gemm256_kernel<1><<<dim3(INTER / 256, T_SEQ / 256, 1), 512, LDS_BYTES, stream>>>(
      xn2, w3_b, vbuf, T_SEQ, INTER, HIDN, HIDN);
  silu_mul_kernel<<<2048, 256, 0, stream>>>(ubuf, vbuf, gbuf, (long)T_SEQ * INTER);
  // W2: M=2048 N=4096 K=14336, split-K=2, then combine with hbuf residual
  gemm256_kernel<0><<<dim3(HIDN / 256, T_SEQ / 256, 2), 512, LDS_BYTES, stream>>>(
      gbuf, w2_b, pbuf, T_SEQ, HIDN, INTER, INTER / 2);
  add3_kernel<<<2048, 256, 0, stream>>>(pbuf, hbuf, (float*)d_out, (long)T_SEQ * HIDN);
}

// Round 4
// 1341.567 us; speedup vs baseline: 1.6786x; 1.0536x over previous
//
#include <hip/hip_runtime.h>
#include <stdint.h>

#define T_SEQ 2048
#define HIDN  4096
#define NH    32
#define NKV   8
#define DH    128
#define INTER 14336
#define QKV_N 6144   /* (32+16)*128 */
#define EPSR  1e-5f
#define SCALE 0.08838834764831845f  /* 1/sqrt(128) */
#define KVB   64

typedef __bf16 bf16x8 __attribute__((ext_vector_type(8)));
typedef float  f32x4  __attribute__((ext_vector_type(4)));

__device__ __forceinline__ f32x4 mfma16(bf16x8 a, bf16x8 b, f32x4 c) {
  return __builtin_amdgcn_mfma_f32_16x16x32_bf16(a, b, c, 0, 0, 0);
}

__device__ __forceinline__ void glds16(const void* g, void* l) {
  __builtin_amdgcn_global_load_lds(
      (__attribute__((address_space(1))) void*)g,
      (__attribute__((address_space(3))) void*)l,
      16, 0, 0);
}

// ---------------- fp32 -> bf16 convert (weights) ----------------
__global__ __launch_bounds__(256) void cvt_bf16_kernel(
    const float* __restrict__ src, __bf16* __restrict__ dst, long n) {
  long stride = (long)gridDim.x * 256 * 8;
  for (long i = ((long)blockIdx.x * 256 + threadIdx.x) * 8; i < n; i += stride) {
    float4 a = *(const float4*)(src + i);
    float4 b = *(const float4*)(src + i + 4);
    bf16x8 o;
    o[0]=(__bf16)a.x; o[1]=(__bf16)a.y; o[2]=(__bf16)a.z; o[3]=(__bf16)a.w;
    o[4]=(__bf16)b.x; o[5]=(__bf16)b.y; o[6]=(__bf16)b.z; o[7]=(__bf16)b.w;
    *(bf16x8*)(dst + i) = o;
  }
}

// ---------------- RMSNorm: fp32 in -> bf16 out ----------------
__global__ __launch_bounds__(256) void rmsnorm_kernel(
    const float* __restrict__ x, const float* __restrict__ w,
    __bf16* __restrict__ y) {
  const int row = blockIdx.x, tid = threadIdx.x;
  const float* xr = x + (size_t)row * HIDN + tid * 16;
  float4 v0 = ((const float4*)xr)[0];
  float4 v1 = ((const float4*)xr)[1];
  float4 v2 = ((const float4*)xr)[2];
  float4 v3 = ((const float4*)xr)[3];
  float ss = v0.x*v0.x + v0.y*v0.y + v0.z*v0.z + v0.w*v0.w
           + v1.x*v1.x + v1.y*v1.y + v1.z*v1.z + v1.w*v1.w
           + v2.x*v2.x + v2.y*v2.y + v2.z*v2.z + v2.w*v2.w
           + v3.x*v3.x + v3.y*v3.y + v3.z*v3.z + v3.w*v3.w;
  #pragma unroll
  for (int off = 32; off >= 1; off >>= 1) ss += __shfl_xor(ss, off, 64);
  __shared__ float red[4];
  if ((tid & 63) == 0) red[tid >> 6] = ss;
  __syncthreads();
  float rn = rsqrtf((red[0] + red[1] + red[2] + red[3]) * (1.0f / HIDN) + EPSR);
  const float* wr = w + tid * 16;
  float4 w0 = ((const float4*)wr)[0];
  float4 w1v = ((const float4*)wr)[1];
  float4 w2v = ((const float4*)wr)[2];
  float4 w3v = ((const float4*)wr)[3];
  bf16x8 o0, o1;
  o0[0]=(__bf16)(v0.x*rn*w0.x);  o0[1]=(__bf16)(v0.y*rn*w0.y);
  o0[2]=(__bf16)(v0.z*rn*w0.z);  o0[3]=(__bf16)(v0.w*rn*w0.w);
  o0[4]=(__bf16)(v1.x*rn*w1v.x); o0[5]=(__bf16)(v1.y*rn*w1v.y);
  o0[6]=(__bf16)(v1.z*rn*w1v.z); o0[7]=(__bf16)(v1.w*rn*w1v.w);
  o1[0]=(__bf16)(v2.x*rn*w2v.x); o1[1]=(__bf16)(v2.y*rn*w2v.y);
  o1[2]=(__bf16)(v2.z*rn*w2v.z); o1[3]=(__bf16)(v2.w*rn*w2v.w);
  o1[4]=(__bf16)(v3.x*rn*w3v.x); o1[5]=(__bf16)(v3.y*rn*w3v.y);
  o1[6]=(__bf16)(v3.z*rn*w3v.z); o1[7]=(__bf16)(v3.w*rn*w3v.w);
  __bf16* yo = y + (size_t)row * HIDN + tid * 16;
  *(bf16x8*)(yo)     = o0;
  *(bf16x8*)(yo + 8) = o1;
}

// ============ 256x256 deep-pipelined GEMM: C = A[M,K] * B[N,K]^T (bf16) ============
template<int EPI>
__global__ __launch_bounds__(512, 2) void gemm256_kernel(
    const __bf16* __restrict__ A, const __bf16* __restrict__ B,
    void* __restrict__ Cout, int M, int N, int Kfull, int KZ) {
  extern __shared__ __align__(16) char smem[];
  const int tid = threadIdx.x;
  const int lane = tid & 63;
  const int wv = tid >> 6;        // 0..7
  const int wm = wv >> 2;         // 0..1
  const int wn = wv & 3;          // 0..3
  const int lr = lane & 15, q = lane >> 4;

  const int gx = gridDim.x, gy = gridDim.y;
  const int nwg = gx * gy;
  const int orig = blockIdx.y * gx + blockIdx.x;
  const int cpx = nwg >> 3;
  const int swz = (orig & 7) * cpx + (orig >> 3);
  const int by = swz % gy, bx = swz / gy;
  const int m0 = by * 256, n0 = bx * 256;
  const int kbase = blockIdx.z * KZ;
  const int NT = KZ >> 5;

  const char* aS[2]; const char* bS[2]; int Lds[2];
  #pragma unroll
  for (int j = 0; j < 2; j++) {
    int L = j * 512 + tid;
    int row = L >> 2;
    int s = (L & 3) ^ ((row >> 1) & 3);
    aS[j] = (const char*)(A + (size_t)(m0 + row) * Kfull + kbase + s * 8);
    bS[j] = (const char*)(B + (size_t)(n0 + row) * Kfull + kbase + s * 8);
    Lds[j] = L * 16;
  }

  const int sA = q ^ ((lr >> 1) & 3);
  int aoff[8], boff[4];
  #pragma unroll
  for (int mt = 0; mt < 8; mt++) aoff[mt] = (wm * 128 + mt * 16 + lr) * 64 + sA * 16;
  #pragma unroll
  for (int nt = 0; nt < 4; nt++) boff[nt] = 16384 + (wn * 64 + nt * 16 + lr) * 64 + sA * 16;

#define STAGE_T(tile, sb) do {                                   \
    char* _b = smem + (sb) * 32768;                              \
    size_t _ko = (size_t)(tile) * 64;                            \
    glds16(aS[0] + _ko, _b + Lds[0]);                            \
    glds16(aS[1] + _ko, _b + Lds[1]);                            \
    glds16(bS[0] + _ko, _b + 16384 + Lds[0]);                    \
    glds16(bS[1] + _ko, _b + 16384 + Lds[1]);                    \
  } while (0)

#define GBODY(VMC, DOST) do {                                    \
    if (DOST) { STAGE_T(t + 3, sbufi); sbufi = (sbufi == 4) ? 0 : sbufi + 1; } \
    asm volatile("s_waitcnt vmcnt(" #VMC ")" ::: "memory");      \
    __builtin_amdgcn_s_barrier();                                \
    asm volatile("" ::: "memory");                               \
    __builtin_amdgcn_sched_barrier(0);                           \
    { const char* _bA = smem + bufi * 32768;                     \
      bf16x8 bf[4], af[8];                                       \
      _Pragma("unroll") for (int nt = 0; nt < 4; nt++)           \
        bf[nt] = *(const bf16x8*)(_bA + boff[nt]);               \
      _Pragma("unroll") for (int mt = 0; mt < 8; mt++)           \
        af[mt] = *(const bf16x8*)(_bA + aoff[mt]);               \
      __builtin_amdgcn_s_setprio(1);                             \
      _Pragma("unroll") for (int mt = 0; mt < 8; mt++)           \
        _Pragma("unroll") for (int nt = 0; nt < 4; nt++)         \
          acc[mt][nt] = mfma16(af[mt], bf[nt], acc[mt][nt]);     \
      __builtin_amdgcn_s_setprio(0); }                           \
    bufi = (bufi == 4) ? 0 : bufi + 1;                           \
  } while (0)

  f32x4 acc[8][4] = {};
  STAGE_T(0, 0); STAGE_T(1, 1); STAGE_T(2, 2);
  int bufi = 0, sbufi = 3;
  for (int t = 0; t < NT - 3; ++t) GBODY(12, true);
  { int t = 0; (void)t;
    GBODY(8, false); GBODY(4, false); GBODY(0, false); }
#undef STAGE_T
#undef GBODY

  #pragma unroll
  for (int mt = 0; mt < 8; mt++) {
    #pragma unroll
    for (int r = 0; r < 4; r++) {
      int rr = m0 + wm * 128 + mt * 16 + q * 4 + r;
      #pragma unroll
      for (int nt = 0; nt < 4; nt++) {
        int cc = n0 + wn * 64 + nt * 16 + lr;
        size_t ix = (size_t)rr * N + cc;
        float val = acc[mt][nt][r];
        if (EPI == 0) ((float*)Cout)[(size_t)blockIdx.z * M * N + ix] = val;
        else          ((__bf16*)Cout)[ix] = (__bf16)val;
      }
    }
  }
}

// ---------------- split-K combine: out = p[0] + p[1] + resid ----------------
__global__ __launch_bounds__(256) void add3_kernel(
    const float* __restrict__ p, const float* __restrict__ r,
    float* __restrict__ o, long n) {
  long stride = (long)gridDim.x * 1024;
  for (long i = ((long)blockIdx.x * 256 + threadIdx.x) * 4; i < n; i += stride) {
    float4 a = *(const float4*)(p + i);
    float4 b = *(const float4*)(p + n + i);
    float4 c = *(const float4*)(r + i);
    float4 o4;
    o4.x = a.x + b.x + c.x; o4.y = a.y + b.y + c.y;
    o4.z = a.z + b.z + c.z; o4.w = a.w + b.w + c.w;
    *(float4*)(o + i) = o4;
  }
}

// ---------------- RoPE: qkv(bf16) -> q_r, k_r (bf16) ----------------
__global__ __launch_bounds__(256) void rope_kernel(
    const __bf16* __restrict__ qkv, __bf16* __restrict__ q_r,
    __bf16* __restrict__ k_r) {
  const int t = blockIdx.x, tid = threadIdx.x;
  __shared__ float cs[64], sn[64];
  if (tid < 64) {
    float inv = exp2f(-(float)tid * (19.931568569324174f / 64.0f)); // theta=1e6
    float f = (float)t * inv;
    cs[tid] = cosf(f);
    sn[tid] = sinf(f);
  }
  __syncthreads();
  const __bf16* row = qkv + (size_t)t * QKV_N;
  for (int it = tid; it < 40 * 64; it += 256) {
    int hh = it >> 6, i = it & 63;
    float x1 = (float)row[hh * 128 + i];
    float x2 = (float)row[hh * 128 + 64 + i];
    float c = cs[i], s = sn[i];
    float o1 = x1 * c - x2 * s;
    float o2 = x2 * c + x1 * s;
    if (hh < NH) {
      __bf16* qo = q_r + (size_t)t * HIDN + hh * 128;
      qo[i] = (__bf16)o1;
      qo[64 + i] = (__bf16)o2;
    } else {
      __bf16* ko = k_r + (size_t)t * (NKV * DH) + (hh - NH) * 128;
      ko[i] = (__bf16)o1;
      ko[64 + i] = (__bf16)o2;
    }
  }
}

// ---------------- V transpose: qkv -> v_t[kh][d][t] ----------------
__global__ __launch_bounds__(256) void vtrans_kernel(
    const __bf16* __restrict__ qkv, __bf16* __restrict__ v_t) {
  __shared__ __bf16 tile[64][136];
  const int tid = threadIdx.x;
  const int t0 = blockIdx.x * 64, kh = blockIdx.y;
  #pragma unroll
  for (int i = 0; i < 4; i++) {
    int u = i * 256 + tid;
    int row = u >> 4, c = (u & 15) * 8;
    *(bf16x8*)&tile[row][c] =
        *(const bf16x8*)(qkv + (size_t)(t0 + row) * QKV_N + (NH + NKV) * DH + kh * DH + c);
  }
  __syncthreads();
  const int d = tid & 127, th = (tid >> 7) * 32;
  #pragma unroll
  for (int j = 0; j < 4; j++) {
    int t = th + j * 8;
    bf16x8 o;
    #pragma unroll
    for (int e = 0; e < 8; e++) o[e] = tile[t + e][d];
    *(bf16x8*)(v_t + ((size_t)kh * DH + d) * T_SEQ + t0 + t) = o;
  }
}

// ---------------- Flash attention v2 (causal, GQA, KVB=64) ----------------
__global__ __launch_bounds__(256) void attn_kernel(
    const __bf16* __restrict__ q_r, const __bf16* __restrict__ k_r,
    const __bf16* __restrict__ v_t, __bf16* __restrict__ attn_o) {
  __shared__ __align__(16) __bf16 Ks[KVB * 128];    // 16KB
  __shared__ __align__(16) __bf16 Vs[128 * KVB];    // 16KB, rows = d
  __shared__ __align__(16) __bf16 Pl[4 * 16 * KVB]; // 8KB

  const int tid = threadIdx.x;
  const int lane = tid & 63, wv = tid >> 6;
  const int lr = lane & 15, g = lane >> 4;
  const int qt = gridDim.x - 1 - blockIdx.x;   // heavy blocks first
  const int h = blockIdx.y;
  const int kh = h >> 2;  // G = 4
  const int q0b = qt * 64;
  const int q0w = q0b + wv * 16;

  bf16x8 qf[4];
  {
    const __bf16* qp = q_r + (size_t)(q0w + lr) * HIDN + h * DH + g * 8;
    #pragma unroll
    for (int kk = 0; kk < 4; kk++) qf[kk] = *(const bf16x8*)(qp + kk * 32);
  }

  f32x4 o[8] = {};
  float mrun[4] = {-1e30f, -1e30f, -1e30f, -1e30f};
  float lrun[4] = {0.f, 0.f, 0.f, 0.f};
  char* PlW = (char*)Pl + wv * 2048;

  for (int kv0 = 0; kv0 < q0b + KVB; kv0 += KVB) {
    __syncthreads();
    // stage K [64][128] via glds16, xor swizzle (row&7)<<4
    #pragma unroll
    for (int i = 0; i < 4; i++) {
      int u = i * 256 + tid;
      int row = u >> 4;
      int cb = ((u & 15) * 16) ^ ((row & 7) << 4);
      glds16((const char*)(k_r + (size_t)(kv0 + row) * (NKV * DH) + kh * DH) + cb,
             (char*)Ks + u * 16);
    }
    // stage Vt [128 d][64 t] via glds16, xor swizzle
    #pragma unroll
    for (int i = 0; i < 4; i++) {
      int u = i * 256 + tid;
      int row = u >> 3;
      int cb = ((u & 7) * 16) ^ ((row & 7) << 4);
      glds16((const char*)(v_t + ((size_t)kh * DH + row) * T_SEQ + kv0) + cb,
             (char*)Vs + u * 16);
    }
    __syncthreads();

    if (q0w + 15 >= kv0) {
      f32x4 s[4] = {};
      #pragma unroll
      for (int kk = 0; kk < 4; kk++) {
        #pragma unroll
        for (int jt = 0; jt < 4; jt++) {
          int krow = jt * 16 + lr;
          int cb = (kk * 64 + g * 16) ^ ((krow & 7) << 4);
          bf16x8 kf = *(const bf16x8*)((char*)Ks + krow * 256 + cb);
          s[jt] = mfma16(qf[kk], kf, s[jt]);
        }
      }
      const bool need_mask = (kv0 + KVB - 1) > q0w;
      #pragma unroll
      for (int r = 0; r < 4; r++) {
        int qpos = q0w + g * 4 + r;
        int prow = g * 4 + r;
        float p[4];
        #pragma unroll
        for (int jt = 0; jt < 4; jt++) {
          float v = s[jt][r] * SCALE;
          if (need_mask && (kv0 + jt * 16 + lr > qpos)) v = -1e30f;
          p[jt] = v;
        }
        float mx = fmaxf(fmaxf(p[0], p[1]), fmaxf(p[2], p[3]));
        #pragma unroll
        for (int off = 1; off < 16; off <<= 1) mx = fmaxf(mx, __shfl_xor(mx, off, 64));
        float mn = fmaxf(mrun[r], mx);
        float corr = __expf(mrun[r] - mn);
        mrun[r] = mn;
        float ps = 0.f;
        #pragma unroll
        for (int jt = 0; jt < 4; jt++) {
          p[jt] = __expf(p[jt] - mn);
          ps += p[jt];
          int cbyte = ((jt * 16 + lr) * 2) ^ ((prow & 7) << 4);
          *(__bf16*)(PlW + prow * 128 + cbyte) = (__bf16)p[jt];
        }
        #pragma unroll
        for (int off = 1; off < 16; off <<= 1) ps += __shfl_xor(ps, off, 64);
        lrun[r] = lrun[r] * corr + ps;
        #pragma unroll
        for (int nt = 0; nt < 8; nt++) o[nt][r] *= corr;
      }
      // PV
      bf16x8 pa[2];
      #pragma unroll
      for (int ks = 0; ks < 2; ks++)
        pa[ks] = *(const bf16x8*)(PlW + lr * 128 + ((g * 16 + ks * 64) ^ ((lr & 7) << 4)));
      #pragma unroll
      for (int nt = 0; nt < 8; nt++) {
        #pragma unroll
        for (int ks = 0; ks < 2; ks++) {
          int vrow = nt * 16 + lr;
          int cb = (ks * 64 + g * 16) ^ ((vrow & 7) << 4);
          bf16x8 vf = *(const bf16x8*)((char*)Vs + vrow * 128 + cb);
          o[nt] = mfma16(pa[ks], vf, o[nt]);
        }
      }
    }
  }

  #pragma unroll
  for (int nt = 0; nt < 8; nt++) {
    #pragma unroll
    for (int r = 0; r < 4; r++) {
      int qrow = q0w + g * 4 + r;
      int d = nt * 16 + lr;
      attn_o[(size_t)qrow * HIDN + h * DH + d] = (__bf16)(o[nt][r] / lrun[r]);
    }
  }
}

// ---------------- SwiGLU elementwise: g = silu(u) * v ----------------
__global__ __launch_bounds__(256) void silu_mul_kernel(
    const __bf16* __restrict__ u, const __bf16* __restrict__ v,
    __bf16* __restrict__ g, long n) {
  long stride = (long)gridDim.x * 256 * 8;
  for (long i = ((long)blockIdx.x * 256 + threadIdx.x) * 8; i < n; i += stride) {
    bf16x8 uu = *(const bf16x8*)(u + i);
    bf16x8 vv = *(const bf16x8*)(v + i);
    bf16x8 gg;
    #pragma unroll
    for (int j = 0; j < 8; j++) {
      float x = (float)uu[j];
      float y = (float)vv[j];
      float sl = x / (1.0f + __expf(-x));
      gg[j] = (__bf16)(sl * y);
    }
    *(bf16x8*)(g + i) = gg;
  }
}

extern "C" void kernel_launch(void* const* d_in, const int* in_sizes, int n_in,
                              void* d_out, int out_size, void* d_ws, size_t ws_size,
                              hipStream_t stream) {
  const float* hidden = (const float*)d_in[0];
  const float* wqkv = (const float*)d_in[2];
  const float* wo   = (const float*)d_in[3];
  const float* w1   = (const float*)d_in[4];
  const float* w3   = (const float*)d_in[5];
  const float* w2   = (const float*)d_in[6];
  const float* anw  = (const float*)d_in[7];
  const float* fnw  = (const float*)d_in[8];

  char* ws = (char*)d_ws;
  const size_t SZ_XN   = (size_t)T_SEQ * HIDN * 2;      // 16,777,216
  const size_t SZ_QKV  = (size_t)T_SEQ * QKV_N * 2;     // 25,165,824
  const size_t SZ_KR   = (size_t)T_SEQ * NKV * DH * 2;  //  4,194,304
  const size_t SZ_H    = (size_t)T_SEQ * HIDN * 4;      // 33,554,432
  const size_t SZ_UV   = (size_t)T_SEQ * INTER * 2;     // 58,720,256

  const size_t W_QKV = (size_t)QKV_N * HIDN * 2;   // 50,331,648
  const size_t W_O   = (size_t)HIDN * HIDN * 2;    // 33,554,432
  const size_t W_I   = (size_t)INTER * HIDN * 2;   // 117,440,512
  const size_t W_TOTAL = W_QKV + W_O + 3 * W_I;    // 436,207,616

  char* act = ws + W_TOTAL;

  __bf16* xn1    = (__bf16*)(act);
  __bf16* qkv    = (__bf16*)(act + SZ_XN);
  __bf16* q_r    = (__bf16*)(act + SZ_XN + SZ_QKV);
  __bf16* ubuf   = (__bf16*)(act);                      // overlays xn1|qkv|q_r
  __bf16* k_r    = (__bf16*)(act + SZ_UV);
  __bf16* attn_o = (__bf16*)(act + SZ_UV + SZ_KR);
  float*  hbuf   = (float*) (act + SZ_UV + SZ_KR + SZ_XN);
  __bf16* v_t    = (__bf16*)(act + SZ_UV + SZ_KR + SZ_XN);  // overlays hbuf (dead until O-proj)
  __bf16* xn2    = (__bf16*)(act + SZ_UV + SZ_KR + SZ_XN + SZ_H);
  __bf16* vbuf   = (__bf16*)(act + SZ_UV + SZ_KR + SZ_XN + SZ_H + SZ_XN);
  __bf16* gbuf   = ubuf;
  float*  pbuf   = (float*)(act + SZ_UV + SZ_KR + SZ_XN + SZ_H);  // split-K partials

  __bf16* wqkv_b = (__bf16*)(ws);
  __bf16* wo_b   = (__bf16*)(ws + W_QKV);
  __bf16* w1_b   = (__bf16*)(ws + W_QKV + W_O);
  __bf16* w3_b   = (__bf16*)(ws + W_QKV + W_O + W_I);
  __bf16* w2_b   = (__bf16*)(ws + W_QKV + W_O + 2 * W_I);

  const int LDS_BYTES = 163840;
  hipFuncSetAttribute((const void*)gemm256_kernel<0>,
                      hipFuncAttributeMaxDynamicSharedMemorySize, LDS_BYTES);
  hipFuncSetAttribute((const void*)gemm256_kernel<1>,
                      hipFuncAttributeMaxDynamicSharedMemorySize, LDS_BYTES);

  cvt_bf16_kernel<<<2048, 256, 0, stream>>>(wqkv, wqkv_b, (long)QKV_N * HIDN);
  cvt_bf16_kernel<<<2048, 256, 0, stream>>>(wo,   wo_b,   (long)HIDN * HIDN);
  cvt_bf16_kernel<<<2048, 256, 0, stream>>>(w1,   w1_b,   (long)INTER * HIDN);
  cvt_bf16_kernel<<<2048, 256, 0, stream>>>(w3,   w3_b,   (long)INTER * HIDN);
  cvt_bf16_kernel<<<2048, 256, 0, stream>>>(w2,   w2_b,   (long)HIDN * INTER);

  rmsnorm_kernel<<<T_SEQ, 256, 0, stream>>>(hidden, anw, xn1);
  gemm256_kernel<1><<<dim3(QKV_N / 256, T_SEQ / 256, 1), 512, LDS_BYTES, stream>>>(
      xn1, wqkv_b, qkv, T_SEQ, QKV_N, HIDN, HIDN);
  rope_kernel<<<T_SEQ, 256, 0, stream>>>(qkv, q_r, k_r);
  vtrans_kernel<<<dim3(T_SEQ / 64, NKV), 256, 0, stream>>>(qkv, v_t);
  attn_kernel<<<dim3(T_SEQ / 64, NH), 256, 0, stream>>>(q_r, k_r, v_t, attn_o);
  gemm256_kernel<0><<<dim3(HIDN / 256, T_SEQ / 256, 2), 512, LDS_BYTES, stream>>>(
      attn_o, wo_b, pbuf, T_SEQ, HIDN, HIDN, HIDN / 2);
  add3_kernel<<<2048, 256, 0, stream>>>(pbuf, hidden, hbuf, (long)T_SEQ * HIDN);
  rmsnorm_kernel<<<T_SEQ, 256, 0, stream>>>(hbuf, fnw, xn2);
  gemm256_kernel<1><<<dim3(INTER / 256, T_SEQ / 256, 1), 512, LDS_BYTES, stream>>>(
      xn2, w1_b, ubuf, T_SEQ, INTER, HIDN, HIDN);
  gemm256_kernel<1><<<dim3(INTER / 256, T_SEQ / 256, 1), 512, LDS_BYTES, stream>>>(
      xn2, w3_b, vbuf, T_SEQ, INTER, HIDN, HIDN);
  silu_mul_kernel<<<2048, 256, 0, stream>>>(ubuf, vbuf, gbuf, (long)T_SEQ * INTER);
  gemm256_kernel<0><<<dim3(HIDN / 256, T_SEQ / 256, 2), 512, LDS_BYTES, stream>>>(
      gbuf, w2_b, pbuf, T_SEQ, HIDN, INTER, INTER / 2);
  add3_kernel<<<2048, 256, 0, stream>>>(pbuf, hbuf, (float*)d_out, (long)T_SEQ * HIDN);
}

// Round 5
// 1325.554 us; speedup vs baseline: 1.6989x; 1.0121x over previous
//
#include <hip/hip_runtime.h>
#include <stdint.h>

#define T_SEQ 2048
#define HIDN  4096
#define NH    32
#define NKV   8
#define DH    128
#define INTER 14336
#define QKV_N 6144   /* (32+16)*128 */
#define EPSR  1e-5f
#define SCALE 0.08838834764831845f  /* 1/sqrt(128) */
#define KVB   64

typedef __bf16 bf16x8 __attribute__((ext_vector_type(8)));
typedef float  f32x4  __attribute__((ext_vector_type(4)));

__device__ __forceinline__ f32x4 mfma16(bf16x8 a, bf16x8 b, f32x4 c) {
  return __builtin_amdgcn_mfma_f32_16x16x32_bf16(a, b, c, 0, 0, 0);
}

__device__ __forceinline__ void glds16(const void* g, void* l) {
  __builtin_amdgcn_global_load_lds(
      (__attribute__((address_space(1))) void*)g,
      (__attribute__((address_space(3))) void*)l,
      16, 0, 0);
}

// ---------------- fp32 -> bf16 convert (weights) ----------------
__global__ __launch_bounds__(256) void cvt_bf16_kernel(
    const float* __restrict__ src, __bf16* __restrict__ dst, long n) {
  long stride = (long)gridDim.x * 256 * 8;
  for (long i = ((long)blockIdx.x * 256 + threadIdx.x) * 8; i < n; i += stride) {
    float4 a = *(const float4*)(src + i);
    float4 b = *(const float4*)(src + i + 4);
    bf16x8 o;
    o[0]=(__bf16)a.x; o[1]=(__bf16)a.y; o[2]=(__bf16)a.z; o[3]=(__bf16)a.w;
    o[4]=(__bf16)b.x; o[5]=(__bf16)b.y; o[6]=(__bf16)b.z; o[7]=(__bf16)b.w;
    *(bf16x8*)(dst + i) = o;
  }
}

// ---------------- RMSNorm: fp32 in -> bf16 out ----------------
__global__ __launch_bounds__(256) void rmsnorm_kernel(
    const float* __restrict__ x, const float* __restrict__ w,
    __bf16* __restrict__ y) {
  const int row = blockIdx.x, tid = threadIdx.x;
  const float* xr = x + (size_t)row * HIDN + tid * 16;
  float4 v0 = ((const float4*)xr)[0];
  float4 v1 = ((const float4*)xr)[1];
  float4 v2 = ((const float4*)xr)[2];
  float4 v3 = ((const float4*)xr)[3];
  float ss = v0.x*v0.x + v0.y*v0.y + v0.z*v0.z + v0.w*v0.w
           + v1.x*v1.x + v1.y*v1.y + v1.z*v1.z + v1.w*v1.w
           + v2.x*v2.x + v2.y*v2.y + v2.z*v2.z + v2.w*v2.w
           + v3.x*v3.x + v3.y*v3.y + v3.z*v3.z + v3.w*v3.w;
  #pragma unroll
  for (int off = 32; off >= 1; off >>= 1) ss += __shfl_xor(ss, off, 64);
  __shared__ float red[4];
  if ((tid & 63) == 0) red[tid >> 6] = ss;
  __syncthreads();
  float rn = rsqrtf((red[0] + red[1] + red[2] + red[3]) * (1.0f / HIDN) + EPSR);
  const float* wr = w + tid * 16;
  float4 w0 = ((const float4*)wr)[0];
  float4 w1v = ((const float4*)wr)[1];
  float4 w2v = ((const float4*)wr)[2];
  float4 w3v = ((const float4*)wr)[3];
  bf16x8 o0, o1;
  o0[0]=(__bf16)(v0.x*rn*w0.x);  o0[1]=(__bf16)(v0.y*rn*w0.y);
  o0[2]=(__bf16)(v0.z*rn*w0.z);  o0[3]=(__bf16)(v0.w*rn*w0.w);
  o0[4]=(__bf16)(v1.x*rn*w1v.x); o0[5]=(__bf16)(v1.y*rn*w1v.y);
  o0[6]=(__bf16)(v1.z*rn*w1v.z); o0[7]=(__bf16)(v1.w*rn*w1v.w);
  o1[0]=(__bf16)(v2.x*rn*w2v.x); o1[1]=(__bf16)(v2.y*rn*w2v.y);
  o1[2]=(__bf16)(v2.z*rn*w2v.z); o1[3]=(__bf16)(v2.w*rn*w2v.w);
  o1[4]=(__bf16)(v3.x*rn*w3v.x); o1[5]=(__bf16)(v3.y*rn*w3v.y);
  o1[6]=(__bf16)(v3.z*rn*w3v.z); o1[7]=(__bf16)(v3.w*rn*w3v.w);
  __bf16* yo = y + (size_t)row * HIDN + tid * 16;
  *(bf16x8*)(yo)     = o0;
  *(bf16x8*)(yo + 8) = o1;
}

// ============ 256x256 8-phase GEMM: C = A[M,K] * B[N,K]^T (bf16) ============
// 512 thr / 8 waves (2Mx4N), wave tile 128x64, BK=64, 2 K-tiles per iteration.
// LDS 128KB: buf b in {0,1}: A halves [b*64K + kh*16K), B halves [b*64K+32K + kh*16K).
// k-half-contiguous layout, 64B rows, slot swizzle s_stored = s ^ ((row>>1)&3)
// (inverse-swizzled glds source, linear dest; same XOR on ds_read side).
// Per phase: {4|8 ds_read_b128} {stage 1 matrix-half: 2 glds16} {vmcnt(8) odd}
// {s_barrier} {lgkmcnt(0)+sched_barrier} {setprio(1) 16 MFMA setprio(0)} {s_barrier}.
// EPI: 0 = write f32 partial at Cout + z*M*N, 1 = write bf16
template<int EPI>
__global__ __launch_bounds__(512, 2) void gemm256_kernel(
    const __bf16* __restrict__ A, const __bf16* __restrict__ B,
    void* __restrict__ Cout, int M, int N, int Kfull, int KZ) {
  extern __shared__ __align__(16) char smem[];
  const int tid = threadIdx.x;
  const int lane = tid & 63;
  const int wv = tid >> 6;        // 0..7
  const int wm = wv >> 2;         // 0..1
  const int wn = wv & 3;          // 0..3
  const int lr = lane & 15, ql = lane >> 4;

  const int gx = gridDim.x, gy = gridDim.y;
  const int nwg = gx * gy;
  const int orig = blockIdx.y * gx + blockIdx.x;
  const int cpx = nwg >> 3;
  const int swz = (orig & 7) * cpx + (orig >> 3);
  const int by = swz % gy, bx = swz / gy;
  const int m0 = by * 256, n0 = bx * 256;
  const int kbase = blockIdx.z * KZ;
  const int NT = KZ >> 6;                  // BK=64 K-tiles (even for all shapes)

  // ---- staging addresses: per phase each thread stages 2x16B of one matrix-half
  const int u0 = tid, u1 = tid + 512;
  const int r0 = u0 >> 2, r1 = u1 >> 2;
  const int p0 = (u0 & 3) ^ ((r0 >> 1) & 3);
  const int p1 = (u1 & 3) ^ ((r1 >> 1) & 3);
  const char* aR0 = (const char*)(A + (size_t)(m0 + r0) * Kfull + kbase) + p0 * 16;
  const char* aR1 = (const char*)(A + (size_t)(m0 + r1) * Kfull + kbase) + p1 * 16;
  const char* bR0 = (const char*)(B + (size_t)(n0 + r0) * Kfull + kbase) + p0 * 16;
  const char* bR1 = (const char*)(B + (size_t)(n0 + r1) * Kfull + kbase) + p1 * 16;
  const int d0 = u0 * 16, d1 = u1 * 16;

  // ---- fragment read offsets (within a 16KB k-half region)
  const int sA = ql ^ ((lr >> 1) & 3);
  int aoff[8], boff[4];
  #pragma unroll
  for (int mt = 0; mt < 8; mt++) aoff[mt] = (wm * 128 + mt * 16 + lr) * 64 + sA * 16;
  #pragma unroll
  for (int nt = 0; nt < 4; nt++) boff[nt] = (wn * 64 + nt * 16 + lr) * 64 + sA * 16;

#define STAGE_A(t, kh, b) do {                                         \
    const size_t _o = (size_t)(t) * 128 + (kh) * 64;                   \
    glds16(aR0 + _o, smem + (b) * 65536 + (kh) * 16384 + d0);          \
    glds16(aR1 + _o, smem + (b) * 65536 + (kh) * 16384 + d1);          \
  } while (0)
#define STAGE_B(t, kh, b) do {                                         \
    const size_t _o = (size_t)(t) * 128 + (kh) * 64;                   \
    glds16(bR0 + _o, smem + (b) * 65536 + 32768 + (kh) * 16384 + d0);  \
    glds16(bR1 + _o, smem + (b) * 65536 + 32768 + (kh) * 16384 + d1);  \
  } while (0)
#define LDA4(dst, mb, b, ks) do {                                      \
    const char* _p = smem + (b) * 65536 + (ks) * 16384;                \
    dst[0] = *(const bf16x8*)(_p + aoff[(mb) + 0]);                    \
    dst[1] = *(const bf16x8*)(_p + aoff[(mb) + 1]);                    \
    dst[2] = *(const bf16x8*)(_p + aoff[(mb) + 2]);                    \
    dst[3] = *(const bf16x8*)(_p + aoff[(mb) + 3]);                    \
  } while (0)
#define LDB4(b, ks) do {                                               \
    const char* _p = smem + (b) * 65536 + 32768 + (ks) * 16384;        \
    bfr[0] = *(const bf16x8*)(_p + boff[0]);                           \
    bfr[1] = *(const bf16x8*)(_p + boff[1]);                           \
    bfr[2] = *(const bf16x8*)(_p + boff[2]);                           \
    bfr[3] = *(const bf16x8*)(_p + boff[3]);                           \
  } while (0)
#define VMW8() asm volatile("s_waitcnt vmcnt(8)" ::: "memory")
#define BAR()  __builtin_amdgcn_s_barrier()
#define WAITK() do { asm volatile("s_waitcnt lgkmcnt(0)" ::: "memory"); \
    __builtin_amdgcn_sched_barrier(0); } while (0)
#define MFMA16(mb, AF) do {                                            \
    __builtin_amdgcn_s_setprio(1);                                     \
    _Pragma("unroll") for (int _m = 0; _m < 4; _m++)                   \
      _Pragma("unroll") for (int _n = 0; _n < 4; _n++)                 \
        acc[(mb) + _m][_n] = mfma16(AF[_m], bfr[_n], acc[(mb) + _m][_n]); \
    __builtin_amdgcn_s_setprio(0);                                     \
  } while (0)

  f32x4 acc[8][4] = {};
  bf16x8 afA[4], afB[4], bfr[4];

  // prologue: 6 matrix-halves (12 loads): tile0.kh0, tile0.kh1, tile1.kh0
  STAGE_A(0, 0, 0); STAGE_B(0, 0, 0);
  STAGE_A(0, 1, 0); STAGE_B(0, 1, 0);
  STAGE_A(1, 0, 1); STAGE_B(1, 0, 1);
  VMW8();   // first 4 loads (tile0.kh0) landed
  BAR();

  const int NI = NT >> 1;
  for (int i = 0; i < NI; ++i) {
    const int t1 = 2 * i + 1;
    const int s2 = (2 * i + 2 < NT) ? 2 * i + 2 : NT - 1;
    const int s3 = (2 * i + 3 < NT) ? 2 * i + 3 : NT - 1;
    // P0: reads buf0.kh0 (af0-3 + bf); stage A(t1).kh1 -> buf1
    LDA4(afA, 0, 0, 0); LDB4(0, 0);
    STAGE_A(t1, 1, 1);
    BAR(); WAITK(); MFMA16(0, afA); BAR();
    // P1: reads af4-7 buf0.kh0; stage B(t1).kh1 -> buf1; vmcnt(8)
    LDA4(afB, 4, 0, 0);
    STAGE_B(t1, 1, 1);
    VMW8(); BAR(); WAITK(); MFMA16(4, afB); BAR();
    // P2: reads buf0.kh1; stage A(s2).kh0 -> buf0
    LDA4(afA, 0, 0, 1); LDB4(0, 1);
    STAGE_A(s2, 0, 0);
    BAR(); WAITK(); MFMA16(0, afA); BAR();
    // P3
    LDA4(afB, 4, 0, 1);
    STAGE_B(s2, 0, 0);
    VMW8(); BAR(); WAITK(); MFMA16(4, afB); BAR();
    // P4: reads buf1.kh0; stage A(s2).kh1 -> buf0
    LDA4(afA, 0, 1, 0); LDB4(1, 0);
    STAGE_A(s2, 1, 0);
    BAR(); WAITK(); MFMA16(0, afA); BAR();
    // P5
    LDA4(afB, 4, 1, 0);
    STAGE_B(s2, 1, 0);
    VMW8(); BAR(); WAITK(); MFMA16(4, afB); BAR();
    // P6: reads buf1.kh1; stage A(s3).kh0 -> buf1
    LDA4(afA, 0, 1, 1); LDB4(1, 1);
    STAGE_A(s3, 0, 1);
    BAR(); WAITK(); MFMA16(0, afA); BAR();
    // P7
    LDA4(afB, 4, 1, 1);
    STAGE_B(s3, 0, 1);
    VMW8(); BAR(); WAITK(); MFMA16(4, afB); BAR();
  }
  asm volatile("s_waitcnt vmcnt(0)" ::: "memory");

#undef STAGE_A
#undef STAGE_B
#undef LDA4
#undef LDB4
#undef VMW8
#undef BAR
#undef WAITK
#undef MFMA16

  // epilogue
  #pragma unroll
  for (int mt = 0; mt < 8; mt++) {
    #pragma unroll
    for (int r = 0; r < 4; r++) {
      int rr = m0 + wm * 128 + mt * 16 + ql * 4 + r;
      #pragma unroll
      for (int nt = 0; nt < 4; nt++) {
        int cc = n0 + wn * 64 + nt * 16 + lr;
        size_t ix = (size_t)rr * N + cc;
        float val = acc[mt][nt][r];
        if (EPI == 0) ((float*)Cout)[(size_t)blockIdx.z * M * N + ix] = val;
        else          ((__bf16*)Cout)[ix] = (__bf16)val;
      }
    }
  }
}

// ---------------- split-K combine: out = p[0] + p[1] + resid ----------------
__global__ __launch_bounds__(256) void add3_kernel(
    const float* __restrict__ p, const float* __restrict__ r,
    float* __restrict__ o, long n) {
  long stride = (long)gridDim.x * 1024;
  for (long i = ((long)blockIdx.x * 256 + threadIdx.x) * 4; i < n; i += stride) {
    float4 a = *(const float4*)(p + i);
    float4 b = *(const float4*)(p + n + i);
    float4 c = *(const float4*)(r + i);
    float4 o4;
    o4.x = a.x + b.x + c.x; o4.y = a.y + b.y + c.y;
    o4.z = a.z + b.z + c.z; o4.w = a.w + b.w + c.w;
    *(float4*)(o + i) = o4;
  }
}

// ---------------- RoPE: qkv(bf16) -> q_r, k_r (bf16) ----------------
__global__ __launch_bounds__(256) void rope_kernel(
    const __bf16* __restrict__ qkv, __bf16* __restrict__ q_r,
    __bf16* __restrict__ k_r) {
  const int t = blockIdx.x, tid = threadIdx.x;
  __shared__ float cs[64], sn[64];
  if (tid < 64) {
    float inv = exp2f(-(float)tid * (19.931568569324174f / 64.0f)); // theta=1e6
    float f = (float)t * inv;
    cs[tid] = cosf(f);
    sn[tid] = sinf(f);
  }
  __syncthreads();
  const __bf16* row = qkv + (size_t)t * QKV_N;
  for (int it = tid; it < 40 * 64; it += 256) {
    int hh = it >> 6, i = it & 63;
    float x1 = (float)row[hh * 128 + i];
    float x2 = (float)row[hh * 128 + 64 + i];
    float c = cs[i], s = sn[i];
    float o1 = x1 * c - x2 * s;
    float o2 = x2 * c + x1 * s;
    if (hh < NH) {
      __bf16* qo = q_r + (size_t)t * HIDN + hh * 128;
      qo[i] = (__bf16)o1;
      qo[64 + i] = (__bf16)o2;
    } else {
      __bf16* ko = k_r + (size_t)t * (NKV * DH) + (hh - NH) * 128;
      ko[i] = (__bf16)o1;
      ko[64 + i] = (__bf16)o2;
    }
  }
}

// ---------------- V transpose: qkv -> v_t[kh][d][t] ----------------
__global__ __launch_bounds__(256) void vtrans_kernel(
    const __bf16* __restrict__ qkv, __bf16* __restrict__ v_t) {
  __shared__ __bf16 tile[64][136];
  const int tid = threadIdx.x;
  const int t0 = blockIdx.x * 64, kh = blockIdx.y;
  #pragma unroll
  for (int i = 0; i < 4; i++) {
    int u = i * 256 + tid;
    int row = u >> 4, c = (u & 15) * 8;
    *(bf16x8*)&tile[row][c] =
        *(const bf16x8*)(qkv + (size_t)(t0 + row) * QKV_N + (NH + NKV) * DH + kh * DH + c);
  }
  __syncthreads();
  const int d = tid & 127, th = (tid >> 7) * 32;
  #pragma unroll
  for (int j = 0; j < 4; j++) {
    int t = th + j * 8;
    bf16x8 o;
    #pragma unroll
    for (int e = 0; e < 8; e++) o[e] = tile[t + e][d];
    *(bf16x8*)(v_t + ((size_t)kh * DH + d) * T_SEQ + t0 + t) = o;
  }
}

// ---------------- Flash attention v2 (causal, GQA, KVB=64) ----------------
__global__ __launch_bounds__(256) void attn_kernel(
    const __bf16* __restrict__ q_r, const __bf16* __restrict__ k_r,
    const __bf16* __restrict__ v_t, __bf16* __restrict__ attn_o) {
  __shared__ __align__(16) __bf16 Ks[KVB * 128];    // 16KB
  __shared__ __align__(16) __bf16 Vs[128 * KVB];    // 16KB, rows = d
  __shared__ __align__(16) __bf16 Pl[4 * 16 * KVB]; // 8KB

  const int tid = threadIdx.x;
  const int lane = tid & 63, wv = tid >> 6;
  const int lr = lane & 15, g = lane >> 4;
  const int qt = gridDim.x - 1 - blockIdx.x;   // heavy blocks first
  const int h = blockIdx.y;
  const int kh = h >> 2;  // G = 4
  const int q0b = qt * 64;
  const int q0w = q0b + wv * 16;

  bf16x8 qf[4];
  {
    const __bf16* qp = q_r + (size_t)(q0w + lr) * HIDN + h * DH + g * 8;
    #pragma unroll
    for (int kk = 0; kk < 4; kk++) qf[kk] = *(const bf16x8*)(qp + kk * 32);
  }

  f32x4 o[8] = {};
  float mrun[4] = {-1e30f, -1e30f, -1e30f, -1e30f};
  float lrun[4] = {0.f, 0.f, 0.f, 0.f};
  char* PlW = (char*)Pl + wv * 2048;

  for (int kv0 = 0; kv0 < q0b + KVB; kv0 += KVB) {
    __syncthreads();
    // stage K [64][128] via glds16, xor swizzle (row&7)<<4
    #pragma unroll
    for (int i = 0; i < 4; i++) {
      int u = i * 256 + tid;
      int row = u >> 4;
      int cb = ((u & 15) * 16) ^ ((row & 7) << 4);
      glds16((const char*)(k_r + (size_t)(kv0 + row) * (NKV * DH) + kh * DH) + cb,
             (char*)Ks + u * 16);
    }
    // stage Vt [128 d][64 t] via glds16, xor swizzle
    #pragma unroll
    for (int i = 0; i < 4; i++) {
      int u = i * 256 + tid;
      int row = u >> 3;
      int cb = ((u & 7) * 16) ^ ((row & 7) << 4);
      glds16((const char*)(v_t + ((size_t)kh * DH + row) * T_SEQ + kv0) + cb,
             (char*)Vs + u * 16);
    }
    __syncthreads();

    if (q0w + 15 >= kv0) {
      f32x4 s[4] = {};
      #pragma unroll
      for (int kk = 0; kk < 4; kk++) {
        #pragma unroll
        for (int jt = 0; jt < 4; jt++) {
          int krow = jt * 16 + lr;
          int cb = (kk * 64 + g * 16) ^ ((krow & 7) << 4);
          bf16x8 kf = *(const bf16x8*)((char*)Ks + krow * 256 + cb);
          s[jt] = mfma16(qf[kk], kf, s[jt]);
        }
      }
      const bool need_mask = (kv0 + KVB - 1) > q0w;
      #pragma unroll
      for (int r = 0; r < 4; r++) {
        int qpos = q0w + g * 4 + r;
        int prow = g * 4 + r;
        float p[4];
        #pragma unroll
        for (int jt = 0; jt < 4; jt++) {
          float v = s[jt][r] * SCALE;
          if (need_mask && (kv0 + jt * 16 + lr > qpos)) v = -1e30f;
          p[jt] = v;
        }
        float mx = fmaxf(fmaxf(p[0], p[1]), fmaxf(p[2], p[3]));
        #pragma unroll
        for (int off = 1; off < 16; off <<= 1) mx = fmaxf(mx, __shfl_xor(mx, off, 64));
        float mn = fmaxf(mrun[r], mx);
        float corr = __expf(mrun[r] - mn);
        mrun[r] = mn;
        float ps = 0.f;
        #pragma unroll
        for (int jt = 0; jt < 4; jt++) {
          p[jt] = __expf(p[jt] - mn);
          ps += p[jt];
          int cbyte = ((jt * 16 + lr) * 2) ^ ((prow & 7) << 4);
          *(__bf16*)(PlW + prow * 128 + cbyte) = (__bf16)p[jt];
        }
        #pragma unroll
        for (int off = 1; off < 16; off <<= 1) ps += __shfl_xor(ps, off, 64);
        lrun[r] = lrun[r] * corr + ps;
        #pragma unroll
        for (int nt = 0; nt < 8; nt++) o[nt][r] *= corr;
      }
      // PV
      bf16x8 pa[2];
      #pragma unroll
      for (int ks = 0; ks < 2; ks++)
        pa[ks] = *(const bf16x8*)(PlW + lr * 128 + ((g * 16 + ks * 64) ^ ((lr & 7) << 4)));
      #pragma unroll
      for (int nt = 0; nt < 8; nt++) {
        #pragma unroll
        for (int ks = 0; ks < 2; ks++) {
          int vrow = nt * 16 + lr;
          int cb = (ks * 64 + g * 16) ^ ((vrow & 7) << 4);
          bf16x8 vf = *(const bf16x8*)((char*)Vs + vrow * 128 + cb);
          o[nt] = mfma16(pa[ks], vf, o[nt]);
        }
      }
    }
  }

  #pragma unroll
  for (int nt = 0; nt < 8; nt++) {
    #pragma unroll
    for (int r = 0; r < 4; r++) {
      int qrow = q0w + g * 4 + r;
      int d = nt * 16 + lr;
      attn_o[(size_t)qrow * HIDN + h * DH + d] = (__bf16)(o[nt][r] / lrun[r]);
    }
  }
}

// ---------------- SwiGLU elementwise: g = silu(u) * v ----------------
__global__ __launch_bounds__(256) void silu_mul_kernel(
    const __bf16* __restrict__ u, const __bf16* __restrict__ v,
    __bf16* __restrict__ g, long n) {
  long stride = (long)gridDim.x * 256 * 8;
  for (long i = ((long)blockIdx.x * 256 + threadIdx.x) * 8; i < n; i += stride) {
    bf16x8 uu = *(const bf16x8*)(u + i);
    bf16x8 vv = *(const bf16x8*)(v + i);
    bf16x8 gg;
    #pragma unroll
    for (int j = 0; j < 8; j++) {
      float x = (float)uu[j];
      float y = (float)vv[j];
      float sl = x / (1.0f + __expf(-x));
      gg[j] = (__bf16)(sl * y);
    }
    *(bf16x8*)(g + i) = gg;
  }
}

extern "C" void kernel_launch(void* const* d_in, const int* in_sizes, int n_in,
                              void* d_out, int out_size, void* d_ws, size_t ws_size,
                              hipStream_t stream) {
  const float* hidden = (const float*)d_in[0];
  const float* wqkv = (const float*)d_in[2];
  const float* wo   = (const float*)d_in[3];
  const float* w1   = (const float*)d_in[4];
  const float* w3   = (const float*)d_in[5];
  const float* w2   = (const float*)d_in[6];
  const float* anw  = (const float*)d_in[7];
  const float* fnw  = (const float*)d_in[8];

  char* ws = (char*)d_ws;
  const size_t SZ_XN   = (size_t)T_SEQ * HIDN * 2;      // 16,777,216
  const size_t SZ_QKV  = (size_t)T_SEQ * QKV_N * 2;     // 25,165,824
  const size_t SZ_KR   = (size_t)T_SEQ * NKV * DH * 2;  //  4,194,304
  const size_t SZ_H    = (size_t)T_SEQ * HIDN * 4;      // 33,554,432
  const size_t SZ_UV   = (size_t)T_SEQ * INTER * 2;     // 58,720,256

  const size_t W_QKV = (size_t)QKV_N * HIDN * 2;   // 50,331,648
  const size_t W_O   = (size_t)HIDN * HIDN * 2;    // 33,554,432
  const size_t W_I   = (size_t)INTER * HIDN * 2;   // 117,440,512
  const size_t W_TOTAL = W_QKV + W_O + 3 * W_I;    // 436,207,616

  char* act = ws + W_TOTAL;

  __bf16* xn1    = (__bf16*)(act);
  __bf16* qkv    = (__bf16*)(act + SZ_XN);
  __bf16* q_r    = (__bf16*)(act + SZ_XN + SZ_QKV);
  __bf16* ubuf   = (__bf16*)(act);                      // overlays xn1|qkv|q_r
  __bf16* k_r    = (__bf16*)(act + SZ_UV);
  __bf16* attn_o = (__bf16*)(act + SZ_UV + SZ_KR);
  float*  hbuf   = (float*) (act + SZ_UV + SZ_KR + SZ_XN);
  __bf16* v_t    = (__bf16*)(act + SZ_UV + SZ_KR + SZ_XN);  // overlays hbuf (dead until O-proj)
  __bf16* xn2    = (__bf16*)(act + SZ_UV + SZ_KR + SZ_XN + SZ_H);
  __bf16* vbuf   = (__bf16*)(act + SZ_UV + SZ_KR + SZ_XN + SZ_H + SZ_XN);
  __bf16* gbuf   = ubuf;
  float*  pbuf   = (float*)(act + SZ_UV + SZ_KR + SZ_XN + SZ_H);  // split-K partials

  __bf16* wqkv_b = (__bf16*)(ws);
  __bf16* wo_b   = (__bf16*)(ws + W_QKV);
  __bf16* w1_b   = (__bf16*)(ws + W_QKV + W_O);
  __bf16* w3_b   = (__bf16*)(ws + W_QKV + W_O + W_I);
  __bf16* w2_b   = (__bf16*)(ws + W_QKV + W_O + 2 * W_I);

  const int LDS_BYTES = 131072;
  hipFuncSetAttribute((const void*)gemm256_kernel<0>,
                      hipFuncAttributeMaxDynamicSharedMemorySize, LDS_BYTES);
  hipFuncSetAttribute((const void*)gemm256_kernel<1>,
                      hipFuncAttributeMaxDynamicSharedMemorySize, LDS_BYTES);

  cvt_bf16_kernel<<<2048, 256, 0, stream>>>(wqkv, wqkv_b, (long)QKV_N * HIDN);
  cvt_bf16_kernel<<<2048, 256, 0, stream>>>(wo,   wo_b,   (long)HIDN * HIDN);
  cvt_bf16_kernel<<<2048, 256, 0, stream>>>(w1,   w1_b,   (long)INTER * HIDN);
  cvt_bf16_kernel<<<2048, 256, 0, stream>>>(w3,   w3_b,   (long)INTER * HIDN);
  cvt_bf16_kernel<<<2048, 256, 0, stream>>>(w2,   w2_b,   (long)HIDN * INTER);

  rmsnorm_kernel<<<T_SEQ, 256, 0, stream>>>(hidden, anw, xn1);
  gemm256_kernel<1><<<dim3(QKV_N / 256, T_SEQ / 256, 1), 512, LDS_BYTES, stream>>>(
      xn1, wqkv_b, qkv, T_SEQ, QKV_N, HIDN, HIDN);
  rope_kernel<<<T_SEQ, 256, 0, stream>>>(qkv, q_r, k_r);
  vtrans_kernel<<<dim3(T_SEQ / 64, NKV), 256, 0, stream>>>(qkv, v_t);
  attn_kernel<<<dim3(T_SEQ / 64, NH), 256, 0, stream>>>(q_r, k_r, v_t, attn_o);
  gemm256_kernel<0><<<dim3(HIDN / 256, T_SEQ / 256, 2), 512, LDS_BYTES, stream>>>(
      attn_o, wo_b, pbuf, T_SEQ, HIDN, HIDN, HIDN / 2);
  add3_kernel<<<2048, 256, 0, stream>>>(pbuf, hidden, hbuf, (long)T_SEQ * HIDN);
  rmsnorm_kernel<<<T_SEQ, 256, 0, stream>>>(hbuf, fnw, xn2);
  gemm256_kernel<1><<<dim3(INTER / 256, T_SEQ / 256, 1), 512, LDS_BYTES, stream>>>(
      xn2, w1_b, ubuf, T_SEQ, INTER, HIDN, HIDN);
  gemm256_kernel<1><<<dim3(INTER / 256, T_SEQ / 256, 1), 512, LDS_BYTES, stream>>>(
      xn2, w3_b, vbuf, T_SEQ, INTER, HIDN, HIDN);
  silu_mul_kernel<<<2048, 256, 0, stream>>>(ubuf, vbuf, gbuf, (long)T_SEQ * INTER);
  gemm256_kernel<0><<<dim3(HIDN / 256, T_SEQ / 256, 2), 512, LDS_BYTES, stream>>>(
      gbuf, w2_b, pbuf, T_SEQ, HIDN, INTER, INTER / 2);
  add3_kernel<<<2048, 256, 0, stream>>>(pbuf, hbuf, (float*)d_out, (long)T_SEQ * HIDN);
}